// Round 1
// baseline (5470.782 us; speedup 1.0000x reference)
//
#include <hip/hip_runtime.h>
#include <math.h>

#define NN 33
#define NC 2112   // 33*64

// ---- ws float offsets ----
#define OFF_L    0          // 33*33 Laplacian (tgt,src)
#define OFF_L2   1100       // 33*33  2*L@L
#define OFF_UT1  2200       // 64*192 fused cheb1 weights, [d][k], k=(s*64+c)
#define OFF_UT2  14600      // 64*192 fused cheb2 weights
#define OFF_WT0  26900      // 3*192*64 s1_tc2 weights [dt][row][ci]
#define OFF_WT1  63800      // s2_tc1
#define OFF_WT2  100700     // s2_tc2
#define OFF_ST1  139400     // 66 floats: sums / sumsq per node
#define OFF_ST2  139500     // 66 floats
#define OFF_MEAN 139600     // 32*2112
#define OFF_A    207232     // big buffer: 32 * 508 * 2112 floats
#define A_ELEMS  34332672ull
#define SLAB     1077120ull // 510*2112 floats per b of scratch

// =====================================================================
// K0: build Laplacian, 2*L@L, fused/transposed cheb weights, transposed
// tconv weights.  One block, 256 threads.
__global__ __launch_bounds__(256) void k_prep(
    const int* __restrict__ ei,
    const float* __restrict__ cw1, const float* __restrict__ cw2,
    const float* __restrict__ tw0, const float* __restrict__ tw1,
    const float* __restrict__ tw2, float* __restrict__ ws) {
  int tid = threadIdx.x;
  float* L  = ws + OFF_L;
  float* L2 = ws + OFF_L2;
  for (int i = tid; i < NN * NN; i += 256) L[i] = 0.f;
  __syncthreads();
  if (tid == 0) {
    float deg[NN];
    for (int n = 0; n < NN; n++) deg[n] = 0.f;
    for (int e = 0; e < 64; e++) deg[ei[e]] += 1.f;
    float dinv[NN];
    for (int n = 0; n < NN; n++) dinv[n] = deg[n] > 0.f ? rsqrtf(deg[n]) : 0.f;
    for (int e = 0; e < 64; e++) {
      int s = ei[e], t = ei[64 + e];
      L[t * NN + s] -= dinv[s] * dinv[t];
    }
  }
  __syncthreads();
  for (int i = tid; i < NN * NN; i += 256) {
    int r = i / NN, c = i % NN;
    float s = 0.f;
    for (int m = 0; m < NN; m++) s += L[r * NN + m] * L[m * NN + c];
    L2[i] = 2.f * s;
  }
  // fused cheb weights:  U0 = W0 - W2, U1 = W1, U2 = W2 (paired with 2*L@L)
  // transposed layout UT[d*192 + s*64 + c] = U_s[c][d]
  for (int i = tid; i < 12288; i += 256) {
    int d = i / 192, k = i % 192, s = k >> 6, c = k & 63;
    float v1 = cw1[(s * 64 + c) * 64 + d];
    float v2 = cw2[(s * 64 + c) * 64 + d];
    if (s == 0) { v1 -= cw1[(128 + c) * 64 + d]; v2 -= cw2[(128 + c) * 64 + d]; }
    ws[OFF_UT1 + i] = v1;
    ws[OFF_UT2 + i] = v2;
  }
  // tconv weights: raw ((g*64+o)*64+ci)*3+dt  ->  WT[dt*12288 + row*64 + ci]
  for (int i = tid; i < 36864; i += 256) {
    int dt = i / 12288, rc = i % 12288;
    ws[OFF_WT0 + i] = tw0[rc * 3 + dt];
    ws[OFF_WT1 + i] = tw1[rc * 3 + dt];
    ws[OFF_WT2 + i] = tw2[rc * 3 + dt];
  }
}

// =====================================================================
// K1: small gated tconv (Ci=3), x -> HS  (chunk slabs, stride 510 rows)
__global__ __launch_bounds__(256) void k_tconv0(
    const float* __restrict__ x, const float* __restrict__ w,
    const float* __restrict__ bias, float* __restrict__ out,
    int b0, int total) {
  __shared__ float wsm[1728];
  __shared__ float bsm[192];
  int tid = threadIdx.x;
  for (int i = tid; i < 1728; i += 256) wsm[i] = w[i];
  if (tid < 192) bsm[tid] = bias[tid];
  __syncthreads();
  int idx = blockIdx.x * 256 + tid;
  if (idx >= total) return;
  int ch = idx & 63;
  int r = idx >> 6;
  int n = r % NN; r /= NN;
  int t = r % 510;
  int bc = r / 510;
  int b = b0 + bc;
  float aP = bsm[ch], aQ = bsm[64 + ch], aR = bsm[128 + ch];
  const float* xp = x + ((size_t)(b * 512 + t) * NN + n) * 3;
  #pragma unroll
  for (int dt = 0; dt < 3; dt++) {
    float x0 = xp[dt * 99 + 0], x1 = xp[dt * 99 + 1], x2 = xp[dt * 99 + 2];
    aP += x0 * wsm[(ch * 3 + 0) * 3 + dt] + x1 * wsm[(ch * 3 + 1) * 3 + dt] + x2 * wsm[(ch * 3 + 2) * 3 + dt];
    aQ += x0 * wsm[((64 + ch) * 3 + 0) * 3 + dt] + x1 * wsm[((64 + ch) * 3 + 1) * 3 + dt] + x2 * wsm[((64 + ch) * 3 + 2) * 3 + dt];
    aR += x0 * wsm[((128 + ch) * 3 + 0) * 3 + dt] + x1 * wsm[((128 + ch) * 3 + 1) * 3 + dt] + x2 * wsm[((128 + ch) * 3 + 2) * 3 + dt];
  }
  float sg = 1.f / (1.f + __expf(-aQ));
  out[(size_t)(bc * 510 + t) * NC + n * 64 + ch] = fmaxf(aP * sg + aR, 0.f);
}

// =====================================================================
// K2: ChebConv (K=3) + bias + relu.  in: chunk slabs stride 510, out same.
// Per block: 4 consecutive t of one b.  LDS: S[33][192] = [h | Lh | 2LLh],
// Ut[64][196] (padded, conflict-free b128).
__global__ __launch_bounds__(256) void k_cheb(
    const float* __restrict__ in, float* __restrict__ out,
    const float* __restrict__ ws, const float* __restrict__ cbias,
    int Tv, int ng, int utOff) {
  __shared__ float S[NN * 192];
  __shared__ float Ut[64 * 196];
  int tid = threadIdx.x;
  const float* utg = ws + utOff;
  for (int i4 = tid; i4 < 3072; i4 += 256) {
    int d = i4 / 48, k4 = i4 % 48;
    float4 v = *(const float4*)(utg + d * 192 + k4 * 4);
    *(float4*)(Ut + d * 196 + k4 * 4) = v;
  }
  const float* Lg  = ws + OFF_L;
  const float* L2g = ws + OFF_L2;
  int bc = blockIdx.x / ng, tg = blockIdx.x % ng;
  int c = tid & 63;
  int g = __builtin_amdgcn_readfirstlane(tid >> 6);  // wave-uniform -> s_loads of L
  for (int tt = 0; tt < 4; tt++) {
    int t = tg * 4 + tt;
    if (t >= Tv) break;
    const float* ip = in + (size_t)(bc * 510 + t) * NC;
    __syncthreads();
    for (int i4 = tid; i4 < 528; i4 += 256) {
      int n = i4 >> 4, c4 = i4 & 15;
      *(float4*)(S + n * 192 + c4 * 4) = *(const float4*)(ip + n * 64 + c4 * 4);
    }
    __syncthreads();
    // Tx1 = L h ; Tx2 = (2 L@L) h   (written to S columns 64..191)
    float t1v[9], t2v[9];
    #pragma unroll
    for (int j = 0; j < 9; j++) { t1v[j] = 0.f; t2v[j] = 0.f; }
    for (int m = 0; m < NN; m++) {
      float hv = S[m * 192 + c];
      #pragma unroll
      for (int j = 0; j < 9; j++) {
        int n = g + j * 4;
        if (n < NN) {
          t1v[j] += Lg[n * NN + m] * hv;
          t2v[j] += L2g[n * NN + m] * hv;
        }
      }
    }
    #pragma unroll
    for (int j = 0; j < 9; j++) {
      int n = g + j * 4;
      if (n < NN) { S[n * 192 + 64 + c] = t1v[j]; S[n * 192 + 128 + c] = t2v[j]; }
    }
    __syncthreads();
    // out[n][d] = sum_k S[n][k] * Ut[d][k]   (d = c here)
    float acc[9];
    #pragma unroll
    for (int j = 0; j < 9; j++) acc[j] = 0.f;
    for (int k4 = 0; k4 < 48; k4++) {
      float4 u = *(const float4*)(Ut + c * 196 + k4 * 4);
      #pragma unroll
      for (int j = 0; j < 9; j++) {
        int n = g + j * 4;
        if (n < NN) {
          float4 s4 = *(const float4*)(S + n * 192 + k4 * 4);
          acc[j] += s4.x * u.x + s4.y * u.y + s4.z * u.z + s4.w * u.w;
        }
      }
    }
    float bd = cbias[c];
    float* op = out + (size_t)(bc * 510 + t) * NC;
    #pragma unroll
    for (int j = 0; j < 9; j++) {
      int n = g + j * 4;
      if (n < NN) op[n * 64 + c] = fmaxf(acc[j] + bd, 0.f);
    }
  }
}

// =====================================================================
// K3: big gated tconv (Ci=64).  Block = (bc, node n, 64-t tile).
// LDS: Xs[66][64] (broadcast reads), Ws[192][68] (padded -> conflict-free).
// Thread = (out-channel ch, 16 t-positions); 48 fp32 accumulators.
__global__ __launch_bounds__(256) void k_tconv(
    const float* __restrict__ in, int inStride, int Tin,
    const float* __restrict__ wt, const float* __restrict__ bias,
    float* __restrict__ out, int outStride, int Tout) {
  __shared__ float Xs[66 * 64];
  __shared__ float Ws[192 * 68];
  int tid = threadIdx.x;
  int nt = (Tout + 63) >> 6;
  int tpb = NN * nt;
  int bc = blockIdx.x / tpb, r = blockIdx.x % tpb;
  int n = r / nt, tt = r % nt;
  int t0 = tt << 6;
  const float* ip = in + (size_t)bc * inStride * NC + n * 64;
  for (int i4 = tid; i4 < 66 * 16; i4 += 256) {
    int row = i4 >> 4, c4 = i4 & 15;
    float4 v = make_float4(0.f, 0.f, 0.f, 0.f);
    if (t0 + row < Tin) v = *(const float4*)(ip + (size_t)(t0 + row) * NC + c4 * 4);
    *(float4*)(Xs + row * 64 + c4 * 4) = v;
  }
  int ch = tid & 63, pg = tid >> 6;
  float aP[16], aQ[16], aR[16];
  #pragma unroll
  for (int j = 0; j < 16; j++) { aP[j] = 0.f; aQ[j] = 0.f; aR[j] = 0.f; }
  for (int dt = 0; dt < 3; dt++) {
    __syncthreads();
    for (int i4 = tid; i4 < 3072; i4 += 256) {
      int row = i4 >> 4, c4 = i4 & 15;
      float4 v = *(const float4*)(wt + dt * 12288 + row * 64 + c4 * 4);
      *(float4*)(Ws + row * 68 + c4 * 4) = v;
    }
    __syncthreads();
    for (int k4 = 0; k4 < 16; k4++) {
      float4 wp = *(const float4*)(Ws + ch * 68 + k4 * 4);
      float4 wq = *(const float4*)(Ws + (64 + ch) * 68 + k4 * 4);
      float4 wr = *(const float4*)(Ws + (128 + ch) * 68 + k4 * 4);
      #pragma unroll
      for (int j = 0; j < 16; j++) {
        float4 xv = *(const float4*)(Xs + (pg * 16 + j + dt) * 64 + k4 * 4);
        aP[j] += xv.x * wp.x + xv.y * wp.y + xv.z * wp.z + xv.w * wp.w;
        aQ[j] += xv.x * wq.x + xv.y * wq.y + xv.z * wq.z + xv.w * wq.w;
        aR[j] += xv.x * wr.x + xv.y * wr.y + xv.z * wr.z + xv.w * wr.w;
      }
    }
  }
  float bP = bias[ch], bQ = bias[64 + ch], bR = bias[128 + ch];
  #pragma unroll
  for (int j = 0; j < 16; j++) {
    int t = t0 + pg * 16 + j;
    if (t < Tout) {
      float P = aP[j] + bP, Q = aQ[j] + bQ, R = aR[j] + bR;
      float sg = 1.f / (1.f + __expf(-Q));
      out[(size_t)(bc * outStride + t) * NC + n * 64 + ch] = fmaxf(P * sg + R, 0.f);
    }
  }
}

// =====================================================================
// K4: BN stats (sum, sumsq per node) over full batch, into ws via atomics.
__global__ __launch_bounds__(256) void k_bnstats(
    const float* __restrict__ A, int stride, int Tv,
    float* __restrict__ st, int nSlab) {
  __shared__ float ls[66];
  int tid = threadIdx.x;
  if (tid < 66) ls[tid] = 0.f;
  __syncthreads();
  int b = blockIdx.x / nSlab, sl = blockIdx.x % nSlab;
  int t0 = sl * 16;
  int tmax = min(16, Tv - t0);
  for (int p = tid; p < NC; p += 256) {
    int n = p >> 6;
    float s = 0.f, q = 0.f;
    for (int dt = 0; dt < tmax; dt++) {
      float v = A[(size_t)(b * stride + t0 + dt) * NC + p];
      s += v; q += v * v;
    }
    atomicAdd(&ls[n], s);
    atomicAdd(&ls[33 + n], q);
  }
  __syncthreads();
  if (tid < 66) atomicAdd(&st[tid], ls[tid]);
}

// K5: BN apply + relu, in place (stage 1)
__global__ __launch_bounds__(256) void k_bnapply(
    float* __restrict__ A, int stride, int Tv,
    const float* __restrict__ st, const float* __restrict__ gg,
    const float* __restrict__ bb, int total4) {
  int idx = blockIdx.x * 256 + threadIdx.x;
  if (idx >= total4) return;
  int i16 = idx & 15;
  int n = (idx >> 4) % NN;
  int rest = (idx >> 4) / NN;
  int t = rest % Tv, b = rest / Tv;
  float cnt = (float)(32 * Tv * 64);
  float mean = st[n] / cnt;
  float var = st[33 + n] / cnt - mean * mean;
  float sc = rsqrtf(var + 1e-5f) * gg[n];
  float sh = bb[n] - mean * sc;
  float4* p = (float4*)(A + (size_t)(b * stride + t) * NC + n * 64 + i16 * 4);
  float4 v = *p;
  v.x = fmaxf(v.x * sc + sh, 0.f);
  v.y = fmaxf(v.y * sc + sh, 0.f);
  v.z = fmaxf(v.z * sc + sh, 0.f);
  v.w = fmaxf(v.w * sc + sh, 0.f);
  *p = v;
}

// K5b: BN apply + relu + mean over T (stage 2), no materialization.
__global__ __launch_bounds__(256) void k_bnmean(
    const float* __restrict__ A, int stride, int Tv,
    const float* __restrict__ st, const float* __restrict__ gg,
    const float* __restrict__ bb, float* __restrict__ mout) {
  int idx = blockIdx.x * 256 + threadIdx.x;   // 32*2112
  int p = idx % NC, b = idx / NC;
  int n = p >> 6;
  float cnt = (float)(32 * Tv * 64);
  float mean = st[n] / cnt;
  float var = st[33 + n] / cnt - mean * mean;
  float sc = rsqrtf(var + 1e-5f) * gg[n];
  float sh = bb[n] - mean * sc;
  float acc = 0.f;
  const float* ap = A + (size_t)b * stride * NC + p;
  for (int t = 0; t < Tv; t += 4) {
    acc += fmaxf(ap[(size_t)t * NC] * sc + sh, 0.f)
         + fmaxf(ap[(size_t)(t + 1) * NC] * sc + sh, 0.f)
         + fmaxf(ap[(size_t)(t + 2) * NC] * sc + sh, 0.f)
         + fmaxf(ap[(size_t)(t + 3) * NC] * sc + sh, 0.f);
  }
  mout[idx] = acc / (float)Tv;
}

// K6: classifier head.  One block per batch sample.
__global__ __launch_bounds__(256) void k_fc(
    const float* __restrict__ meanb, const float* __restrict__ w1,
    const float* __restrict__ b1, const float* __restrict__ w2,
    const float* __restrict__ b2, float* __restrict__ out) {
  __shared__ float m[NC];
  __shared__ float h[256];
  int tid = threadIdx.x, b = blockIdx.x;
  for (int i4 = tid; i4 < 528; i4 += 256)
    *(float4*)(m + i4 * 4) = *(const float4*)(meanb + b * NC + i4 * 4);
  __syncthreads();
  float acc = b1[tid];
  for (int k = 0; k < NC; k += 8) {
    #pragma unroll
    for (int u = 0; u < 8; u++) acc += m[k + u] * w1[(k + u) * 256 + tid];
  }
  h[tid] = fmaxf(acc, 0.f);
  __syncthreads();
  if (tid < 10) {
    float a = b2[tid];
    for (int k = 0; k < 256; k++) a += h[k] * w2[k * 10 + tid];
    out[b * 10 + tid] = a;
  }
}

// =====================================================================
extern "C" void kernel_launch(void* const* d_in, const int* in_sizes, int n_in,
                              void* d_out, int out_size, void* d_ws, size_t ws_size,
                              hipStream_t stream) {
  const float* x        = (const float*)d_in[0];
  const int*   ei       = (const int*)d_in[1];
  const float* s1_tc1_w = (const float*)d_in[2];
  const float* s1_tc1_b = (const float*)d_in[3];
  const float* s1_cheb_w= (const float*)d_in[4];
  const float* s1_cheb_b= (const float*)d_in[5];
  const float* s1_tc2_w = (const float*)d_in[6];
  const float* s1_tc2_b = (const float*)d_in[7];
  const float* s1_bn_g  = (const float*)d_in[8];
  const float* s1_bn_b  = (const float*)d_in[9];
  const float* s2_tc1_w = (const float*)d_in[10];
  const float* s2_tc1_b = (const float*)d_in[11];
  const float* s2_cheb_w= (const float*)d_in[12];
  const float* s2_cheb_b= (const float*)d_in[13];
  const float* s2_tc2_w = (const float*)d_in[14];
  const float* s2_tc2_b = (const float*)d_in[15];
  const float* s2_bn_g  = (const float*)d_in[16];
  const float* s2_bn_b  = (const float*)d_in[17];
  const float* fc1_w    = (const float*)d_in[18];
  const float* fc1_b    = (const float*)d_in[19];
  const float* fc2_w    = (const float*)d_in[20];
  const float* fc2_b    = (const float*)d_in[21];
  float* ws  = (float*)d_ws;
  float* out = (float*)d_out;

  // pick batch chunk so ws fits: A (137 MB) + 2 * chunk * 4.3 MB scratch
  int chunk = 8;
  while (chunk > 1 &&
         ((size_t)OFF_A + A_ELEMS + (size_t)chunk * SLAB * 2) * 4 > ws_size)
    chunk >>= 1;
  float* A  = ws + OFF_A;
  float* HS = A + A_ELEMS;
  float* CS = HS + (size_t)chunk * SLAB;

  hipMemsetAsync(ws + OFF_ST1, 0, 200 * sizeof(float), stream);
  k_prep<<<1, 256, 0, stream>>>(ei, s1_cheb_w, s2_cheb_w,
                                s1_tc2_w, s2_tc1_w, s2_tc2_w, ws);

  int nchunks = 32 / chunk;
  // ---------------- stage 1 ----------------
  for (int ci = 0; ci < nchunks; ci++) {
    int b0 = ci * chunk;
    int total0 = chunk * 510 * NC;
    k_tconv0<<<(total0 + 255) / 256, 256, 0, stream>>>(x, s1_tc1_w, s1_tc1_b,
                                                       HS, b0, total0);
    int ng1 = (510 + 3) / 4;
    k_cheb<<<chunk * ng1, 256, 0, stream>>>(HS, CS, ws, s1_cheb_b, 510, ng1, OFF_UT1);
    k_tconv<<<chunk * NN * 8, 256, 0, stream>>>(CS, 510, 510, ws + OFF_WT0, s1_tc2_b,
                                                A + (size_t)b0 * 508 * NC, 508, 508);
  }
  int nSlab1 = (508 + 15) / 16;
  k_bnstats<<<32 * nSlab1, 256, 0, stream>>>(A, 508, 508, ws + OFF_ST1, nSlab1);
  int total4a = 32 * 508 * 528;
  k_bnapply<<<(total4a + 255) / 256, 256, 0, stream>>>(A, 508, 508, ws + OFF_ST1,
                                                       s1_bn_g, s1_bn_b, total4a);
  // ---------------- stage 2 ----------------
  for (int ci = 0; ci < nchunks; ci++) {
    int b0 = ci * chunk;
    k_tconv<<<chunk * NN * 8, 256, 0, stream>>>(A + (size_t)b0 * 508 * NC, 508, 508,
                                                ws + OFF_WT1, s2_tc1_b, HS, 510, 506);
    int ng2 = (506 + 3) / 4;
    k_cheb<<<chunk * ng2, 256, 0, stream>>>(HS, CS, ws, s2_cheb_b, 506, ng2, OFF_UT2);
    k_tconv<<<chunk * NN * 8, 256, 0, stream>>>(CS, 510, 506, ws + OFF_WT2, s2_tc2_b,
                                                A + (size_t)b0 * 508 * NC, 508, 504);
  }
  int nSlab2 = (504 + 15) / 16;
  k_bnstats<<<32 * nSlab2, 256, 0, stream>>>(A, 508, 504, ws + OFF_ST2, nSlab2);
  k_bnmean<<<(32 * NC) / 256, 256, 0, stream>>>(A, 508, 504, ws + OFF_ST2,
                                                s2_bn_g, s2_bn_b, ws + OFF_MEAN);
  k_fc<<<32, 256, 0, stream>>>(ws + OFF_MEAN, fc1_w, fc1_b, fc2_w, fc2_b, out);
}

// Round 3
// 4196.307 us; speedup vs baseline: 1.3037x; 1.3037x over previous
//
#include <hip/hip_runtime.h>
#include <math.h>

#define NN 33
#define NC 2112   // 33*64

// ---- ws float offsets ----
#define OFF_L    0          // 33*33 Laplacian (tgt,src)
#define OFF_L2   1100       // 33*33  2*L@L
#define OFF_UP1  2200       // 12288: cheb1 fused weights, swizzled [k4][d][4]
#define OFF_UP2  14600      // 12288: cheb2
#define OFF_WT0  26900      // 36864: s1_tc2 scalar layout [mi][k4][dt][c8][g][e]
#define OFF_WT1  63800      // s2_tc1
#define OFF_WT2  100700     // s2_tc2
#define OFF_ST1  139400     // 66 floats: sums / sumsq per node
#define OFF_ST2  139500     // 66 floats
#define OFF_MEAN 139600     // 32*2112
#define OFF_A    207232     // big buffer: 32 * 508 * 2112 floats
#define A_ELEMS  34332672ull
#define SLAB     1077120ull // 510*2112 floats per b of scratch

// =====================================================================
// K0: build Laplacian, 2*L@L, swizzled cheb weights, scalar-layout tconv
// weights.  One block, 256 threads.
__global__ __launch_bounds__(256) void k_prep(
    const int* __restrict__ ei,
    const float* __restrict__ cw1, const float* __restrict__ cw2,
    const float* __restrict__ tw0, const float* __restrict__ tw1,
    const float* __restrict__ tw2, float* __restrict__ ws) {
  int tid = threadIdx.x;
  float* L  = ws + OFF_L;
  float* L2 = ws + OFF_L2;
  for (int i = tid; i < NN * NN; i += 256) L[i] = 0.f;
  __syncthreads();
  if (tid == 0) {
    float deg[NN];
    for (int n = 0; n < NN; n++) deg[n] = 0.f;
    for (int e = 0; e < 64; e++) deg[ei[e]] += 1.f;
    float dinv[NN];
    for (int n = 0; n < NN; n++) dinv[n] = deg[n] > 0.f ? rsqrtf(deg[n]) : 0.f;
    for (int e = 0; e < 64; e++) {
      int s = ei[e], t = ei[64 + e];
      L[t * NN + s] -= dinv[s] * dinv[t];
    }
  }
  __syncthreads();
  for (int i = tid; i < NN * NN; i += 256) {
    int r = i / NN, c = i % NN;
    float s = 0.f;
    for (int m = 0; m < NN; m++) s += L[r * NN + m] * L[m * NN + c];
    L2[i] = 2.f * s;
  }
  // fused cheb weights:  U0 = W0 - W2 (on h), U1 = W1 (on Lh), U2 = W2 (on 2LLh)
  // swizzled: Up[k4*256 + d*4 + e] = Ufused[k=4*k4+e][d],  k = s*64+c
  for (int i = tid; i < 12288; i += 256) {
    int k4 = i >> 8, d = (i >> 2) & 63, e = i & 3;
    int k = 4 * k4 + e, s = k >> 6, c = k & 63;
    float v1 = cw1[(s * 64 + c) * 64 + d];
    float v2 = cw2[(s * 64 + c) * 64 + d];
    if (s == 0) { v1 -= cw1[(128 + c) * 64 + d]; v2 -= cw2[(128 + c) * 64 + d]; }
    ws[OFF_UP1 + i] = v1;
    ws[OFF_UP2 + i] = v2;
  }
  // tconv scalar layout:
  //   Wsc[((mi*16 + k4)*3 + dt)*96 + c8*12 + g*4 + e]
  //     = raw[((g*64 + mi*8 + c8)*64 + 4*k4 + e)*3 + dt]
  for (int i = tid; i < 36864; i += 256) {
    int e = i & 3;
    int g = (i >> 2) % 3;
    int c8 = (i / 12) & 7;
    int rem = i / 96;
    int dt = rem % 3;
    int k4 = (rem / 3) & 15;
    int mi = rem / 48;
    int src = ((g * 64 + mi * 8 + c8) * 64 + 4 * k4 + e) * 3 + dt;
    ws[OFF_WT0 + i] = tw0[src];
    ws[OFF_WT1 + i] = tw1[src];
    ws[OFF_WT2 + i] = tw2[src];
  }
}

// =====================================================================
// K1: small gated tconv (Ci=3), x -> HS  (chunk slabs, stride 510 rows)
__global__ __launch_bounds__(256) void k_tconv0(
    const float* __restrict__ x, const float* __restrict__ w,
    const float* __restrict__ bias, float* __restrict__ out,
    int b0, int total) {
  __shared__ float wsm[1728];
  __shared__ float bsm[192];
  int tid = threadIdx.x;
  for (int i = tid; i < 1728; i += 256) wsm[i] = w[i];
  if (tid < 192) bsm[tid] = bias[tid];
  __syncthreads();
  int idx = blockIdx.x * 256 + tid;
  if (idx >= total) return;
  int ch = idx & 63;
  int r = idx >> 6;
  int n = r % NN; r /= NN;
  int t = r % 510;
  int bc = r / 510;
  int b = b0 + bc;
  float aP = bsm[ch], aQ = bsm[64 + ch], aR = bsm[128 + ch];
  const float* xp = x + ((size_t)(b * 512 + t) * NN + n) * 3;
  #pragma unroll
  for (int dt = 0; dt < 3; dt++) {
    float x0 = xp[dt * 99 + 0], x1 = xp[dt * 99 + 1], x2 = xp[dt * 99 + 2];
    aP += x0 * wsm[(ch * 3 + 0) * 3 + dt] + x1 * wsm[(ch * 3 + 1) * 3 + dt] + x2 * wsm[(ch * 3 + 2) * 3 + dt];
    aQ += x0 * wsm[((64 + ch) * 3 + 0) * 3 + dt] + x1 * wsm[((64 + ch) * 3 + 1) * 3 + dt] + x2 * wsm[((64 + ch) * 3 + 2) * 3 + dt];
    aR += x0 * wsm[((128 + ch) * 3 + 0) * 3 + dt] + x1 * wsm[((128 + ch) * 3 + 1) * 3 + dt] + x2 * wsm[((128 + ch) * 3 + 2) * 3 + dt];
  }
  float sg = 1.f / (1.f + __expf(-aQ));
  out[(size_t)(bc * 510 + t) * NC + n * 64 + ch] = fmaxf(aP * sg + aR, 0.f);
}

// =====================================================================
// K2: ChebConv (K=3) + bias + relu.  One (b,t) per 128-thread block.
// LDS: only S[33][196] (25.9 KB).  U read from global (swizzled
// [k4][d][4], L1/L2 broadcast).  Register tile: R n-rows x 4 d.
__global__ __launch_bounds__(128) void k_cheb(
    const float* __restrict__ in, float* __restrict__ out,
    const float* __restrict__ ws, const float* __restrict__ cbias,
    int Tv, int upOff) {
  __shared__ float S[NN * 196];
  int tid = threadIdx.x;
  int bc = blockIdx.x / Tv, t = blockIdx.x % Tv;
  const float* ip = in + (size_t)(bc * 510 + t) * NC;
  for (int i4 = tid; i4 < 528; i4 += 128) {
    int n = i4 >> 4, c4 = i4 & 15;
    *(float4*)(S + n * 196 + c4 * 4) = *(const float4*)(ip + n * 64 + c4 * 4);
  }
  int c = tid & 63;
  int half = __builtin_amdgcn_readfirstlane(tid >> 6);  // wave id, uniform
  __syncthreads();
  // ---- prop: Z1 = L h, Z2 = 2LL h into S cols 64..191 ----
  const float* Lg  = ws + OFF_L;
  const float* L2g = ws + OFF_L2;
  int nb = half * 16;
  int cnt = 16 + half;           // wave0: n 0..15, wave1: n 16..32
  float t1[17], t2[17];
  #pragma unroll
  for (int i = 0; i < 17; i++) { t1[i] = 0.f; t2[i] = 0.f; }
  for (int m = 0; m < NN; m++) {
    float hv = S[m * 196 + c];
    #pragma unroll
    for (int i = 0; i < 17; i++) {
      if (i < cnt) {
        t1[i] += Lg[(nb + i) * NN + m] * hv;
        t2[i] += L2g[(nb + i) * NN + m] * hv;
      }
    }
  }
  #pragma unroll
  for (int i = 0; i < 17; i++) {
    if (i < cnt) {
      S[(nb + i) * 196 + 64 + c]  = t1[i];
      S[(nb + i) * 196 + 128 + c] = t2[i];
    }
  }
  __syncthreads();
  // ---- GEMM: out[n][d] = sum_k S[n][k] * U[k][d],  K = 192 ----
  int dg = tid & 15, ng = (tid >> 4) & 3;
  int R = 4 + half;              // wave0 R=4 (n 0..15), wave1 R=5 (n 16..32)
  const float* Up = ws + upOff;
  float acc[5][4];
  #pragma unroll
  for (int r = 0; r < 5; r++)
    #pragma unroll
    for (int u = 0; u < 4; u++) acc[r][u] = 0.f;
  for (int k4 = 0; k4 < 48; k4++) {
    float4 up[4];
    #pragma unroll
    for (int u = 0; u < 4; u++)
      up[u] = *(const float4*)(Up + (size_t)k4 * 256 + (dg + 16 * u) * 4);
    #pragma unroll
    for (int r = 0; r < 5; r++) {
      if (r < R) {
        int n = nb + 4 * r + ng;
        if (n < NN) {
          float4 s4 = *(const float4*)(S + n * 196 + k4 * 4);
          #pragma unroll
          for (int u = 0; u < 4; u++)
            acc[r][u] += s4.x * up[u].x + s4.y * up[u].y +
                         s4.z * up[u].z + s4.w * up[u].w;
        }
      }
    }
  }
  float* op = out + (size_t)(bc * 510 + t) * NC;
  #pragma unroll
  for (int u = 0; u < 4; u++) {
    int d = dg + 16 * u;
    float bd = cbias[d];
    #pragma unroll
    for (int r = 0; r < 5; r++) {
      if (r < R) {
        int n = nb + 4 * r + ng;
        if (n < NN) op[n * 64 + d] = fmaxf(acc[r][u] + bd, 0.f);
      }
    }
  }
}

// =====================================================================
// K3 v3: big gated tconv (Ci=64).  Block = (bc, node n, 64-t tile), 256 thr.
// lane = t within tile; wave = 16 out-channels (2 groups of 8).
// Weights via wave-uniform indices -> scalar loads (no LDS, no VGPR vec).
// X in LDS 66x64 with XOR column swizzle -> minimal-bank b128 reads.
__global__ __launch_bounds__(256) void k_tconv(
    const float* __restrict__ in, int inStride, int Tin,
    const float* __restrict__ wsc, const float* __restrict__ bias,
    float* __restrict__ out, int outStride, int Tout) {
  __shared__ float Xs[66 * 64];
  int tid = threadIdx.x;
  int nt = (Tout + 63) >> 6;
  int tpb = NN * nt;
  int bc = blockIdx.x / tpb, r = blockIdx.x % tpb;
  int n = r / nt, tt = r % nt;
  int t0 = tt << 6;
  const float* ip = in + (size_t)bc * inStride * NC + n * 64;
  for (int i4 = tid; i4 < 1056; i4 += 256) {
    int row = i4 >> 4, c4 = i4 & 15;
    float4 v = make_float4(0.f, 0.f, 0.f, 0.f);
    if (t0 + row < Tin) v = *(const float4*)(ip + (size_t)(t0 + row) * NC + c4 * 4);
    *(float4*)(Xs + row * 64 + ((c4 + row) & 15) * 4) = v;
  }
  __syncthreads();
  int lane = tid & 63;
  int w = __builtin_amdgcn_readfirstlane(tid >> 6);
  int t = t0 + lane;
  float* op = out + (size_t)((size_t)(bc * outStride + t)) * NC + n * 64;
  #pragma unroll
  for (int cc = 0; cc < 2; cc++) {
    int mi = w * 2 + cc;               // 8-channel group, ch = mi*8 + c8
    const float* wb = wsc + mi * 4608; // 16*3*96
    float acc[8][3];
    #pragma unroll
    for (int c8 = 0; c8 < 8; c8++)
      #pragma unroll
      for (int g = 0; g < 3; g++) acc[c8][g] = 0.f;
    for (int k4 = 0; k4 < 16; k4++) {
      #pragma unroll
      for (int dt = 0; dt < 3; dt++) {
        int row = lane + dt;
        float4 xv = *(const float4*)(Xs + row * 64 + ((k4 + row) & 15) * 4);
        const float* wp = wb + (k4 * 3 + dt) * 96;
        #pragma unroll
        for (int c8 = 0; c8 < 8; c8++) {
          #pragma unroll
          for (int g = 0; g < 3; g++) {
            const float* q = wp + c8 * 12 + g * 4;
            acc[c8][g] += xv.x * q[0] + xv.y * q[1] + xv.z * q[2] + xv.w * q[3];
          }
        }
      }
    }
    if (t < Tout) {
      #pragma unroll
      for (int h8 = 0; h8 < 2; h8++) {
        float4 hv;
        float* hp = (float*)&hv;
        #pragma unroll
        for (int j = 0; j < 4; j++) {
          int c8 = h8 * 4 + j;
          int ch = mi * 8 + c8;
          float P = acc[c8][0] + bias[ch];
          float Q = acc[c8][1] + bias[64 + ch];
          float Rv = acc[c8][2] + bias[128 + ch];
          float sg = 1.f / (1.f + __expf(-Q));
          hp[j] = fmaxf(P * sg + Rv, 0.f);
        }
        *(float4*)(op + mi * 8 + h8 * 4) = hv;
      }
    }
  }
}

// =====================================================================
// K4: BN stats (sum, sumsq per node) over full batch, into ws via atomics.
__global__ __launch_bounds__(256) void k_bnstats(
    const float* __restrict__ A, int stride, int Tv,
    float* __restrict__ st, int nSlab) {
  __shared__ float ls[66];
  int tid = threadIdx.x;
  if (tid < 66) ls[tid] = 0.f;
  __syncthreads();
  int b = blockIdx.x / nSlab, sl = blockIdx.x % nSlab;
  int t0 = sl * 16;
  int tmax = min(16, Tv - t0);
  for (int p = tid; p < NC; p += 256) {
    int n = p >> 6;
    float s = 0.f, q = 0.f;
    for (int dt = 0; dt < tmax; dt++) {
      float v = A[(size_t)(b * stride + t0 + dt) * NC + p];
      s += v; q += v * v;
    }
    atomicAdd(&ls[n], s);
    atomicAdd(&ls[33 + n], q);
  }
  __syncthreads();
  if (tid < 66) atomicAdd(&st[tid], ls[tid]);
}

// K5: BN apply + relu, in place (stage 1)
__global__ __launch_bounds__(256) void k_bnapply(
    float* __restrict__ A, int stride, int Tv,
    const float* __restrict__ st, const float* __restrict__ gg,
    const float* __restrict__ bb, int total4) {
  int idx = blockIdx.x * 256 + threadIdx.x;
  if (idx >= total4) return;
  int i16 = idx & 15;
  int n = (idx >> 4) % NN;
  int rest = (idx >> 4) / NN;
  int t = rest % Tv, b = rest / Tv;
  float cnt = (float)(32 * Tv * 64);
  float mean = st[n] / cnt;
  float var = st[33 + n] / cnt - mean * mean;
  float sc = rsqrtf(var + 1e-5f) * gg[n];
  float sh = bb[n] - mean * sc;
  float4* p = (float4*)(A + (size_t)(b * stride + t) * NC + n * 64 + i16 * 4);
  float4 v = *p;
  v.x = fmaxf(v.x * sc + sh, 0.f);
  v.y = fmaxf(v.y * sc + sh, 0.f);
  v.z = fmaxf(v.z * sc + sh, 0.f);
  v.w = fmaxf(v.w * sc + sh, 0.f);
  *p = v;
}

// K5b: BN apply + relu + mean over T (stage 2), no materialization.
__global__ __launch_bounds__(256) void k_bnmean(
    const float* __restrict__ A, int stride, int Tv,
    const float* __restrict__ st, const float* __restrict__ gg,
    const float* __restrict__ bb, float* __restrict__ mout) {
  int idx = blockIdx.x * 256 + threadIdx.x;   // 32*2112
  int p = idx % NC, b = idx / NC;
  int n = p >> 6;
  float cnt = (float)(32 * Tv * 64);
  float mean = st[n] / cnt;
  float var = st[33 + n] / cnt - mean * mean;
  float sc = rsqrtf(var + 1e-5f) * gg[n];
  float sh = bb[n] - mean * sc;
  float acc = 0.f;
  const float* ap = A + (size_t)b * stride * NC + p;
  for (int t = 0; t < Tv; t += 4) {
    acc += fmaxf(ap[(size_t)t * NC] * sc + sh, 0.f)
         + fmaxf(ap[(size_t)(t + 1) * NC] * sc + sh, 0.f)
         + fmaxf(ap[(size_t)(t + 2) * NC] * sc + sh, 0.f)
         + fmaxf(ap[(size_t)(t + 3) * NC] * sc + sh, 0.f);
  }
  mout[idx] = acc / (float)Tv;
}

// K6: classifier head.  One block per batch sample.
__global__ __launch_bounds__(256) void k_fc(
    const float* __restrict__ meanb, const float* __restrict__ w1,
    const float* __restrict__ b1, const float* __restrict__ w2,
    const float* __restrict__ b2, float* __restrict__ out) {
  __shared__ float m[NC];
  __shared__ float h[256];
  int tid = threadIdx.x, b = blockIdx.x;
  for (int i4 = tid; i4 < 528; i4 += 256)
    *(float4*)(m + i4 * 4) = *(const float4*)(meanb + b * NC + i4 * 4);
  __syncthreads();
  float acc = b1[tid];
  for (int k = 0; k < NC; k += 8) {
    #pragma unroll
    for (int u = 0; u < 8; u++) acc += m[k + u] * w1[(k + u) * 256 + tid];
  }
  h[tid] = fmaxf(acc, 0.f);
  __syncthreads();
  if (tid < 10) {
    float a = b2[tid];
    for (int k = 0; k < 256; k++) a += h[k] * w2[k * 10 + tid];
    out[b * 10 + tid] = a;
  }
}

// =====================================================================
extern "C" void kernel_launch(void* const* d_in, const int* in_sizes, int n_in,
                              void* d_out, int out_size, void* d_ws, size_t ws_size,
                              hipStream_t stream) {
  const float* x        = (const float*)d_in[0];
  const int*   ei       = (const int*)d_in[1];
  const float* s1_tc1_w = (const float*)d_in[2];
  const float* s1_tc1_b = (const float*)d_in[3];
  const float* s1_cheb_w= (const float*)d_in[4];
  const float* s1_cheb_b= (const float*)d_in[5];
  const float* s1_tc2_w = (const float*)d_in[6];
  const float* s1_tc2_b = (const float*)d_in[7];
  const float* s1_bn_g  = (const float*)d_in[8];
  const float* s1_bn_b  = (const float*)d_in[9];
  const float* s2_tc1_w = (const float*)d_in[10];
  const float* s2_tc1_b = (const float*)d_in[11];
  const float* s2_cheb_w= (const float*)d_in[12];
  const float* s2_cheb_b= (const float*)d_in[13];
  const float* s2_tc2_w = (const float*)d_in[14];
  const float* s2_tc2_b = (const float*)d_in[15];
  const float* s2_bn_g  = (const float*)d_in[16];
  const float* s2_bn_b  = (const float*)d_in[17];
  const float* fc1_w    = (const float*)d_in[18];
  const float* fc1_b    = (const float*)d_in[19];
  const float* fc2_w    = (const float*)d_in[20];
  const float* fc2_b    = (const float*)d_in[21];
  float* ws  = (float*)d_ws;
  float* out = (float*)d_out;

  // pick batch chunk so ws fits: A (137 MB) + 2 * chunk * 4.3 MB scratch
  int chunk = 8;
  while (chunk > 1 &&
         ((size_t)OFF_A + A_ELEMS + (size_t)chunk * SLAB * 2) * 4 > ws_size)
    chunk >>= 1;
  float* A  = ws + OFF_A;
  float* HS = A + A_ELEMS;
  float* CS = HS + (size_t)chunk * SLAB;

  hipMemsetAsync(ws + OFF_ST1, 0, 200 * sizeof(float), stream);
  k_prep<<<1, 256, 0, stream>>>(ei, s1_cheb_w, s2_cheb_w,
                                s1_tc2_w, s2_tc1_w, s2_tc2_w, ws);

  int nchunks = 32 / chunk;
  // ---------------- stage 1 ----------------
  for (int ci = 0; ci < nchunks; ci++) {
    int b0 = ci * chunk;
    int total0 = chunk * 510 * NC;
    k_tconv0<<<(total0 + 255) / 256, 256, 0, stream>>>(x, s1_tc1_w, s1_tc1_b,
                                                       HS, b0, total0);
    k_cheb<<<chunk * 510, 128, 0, stream>>>(HS, CS, ws, s1_cheb_b, 510, OFF_UP1);
    k_tconv<<<chunk * NN * 8, 256, 0, stream>>>(CS, 510, 510, ws + OFF_WT0, s1_tc2_b,
                                                A + (size_t)b0 * 508 * NC, 508, 508);
  }
  int nSlab1 = (508 + 15) / 16;
  k_bnstats<<<32 * nSlab1, 256, 0, stream>>>(A, 508, 508, ws + OFF_ST1, nSlab1);
  int total4a = 32 * 508 * 528;
  k_bnapply<<<(total4a + 255) / 256, 256, 0, stream>>>(A, 508, 508, ws + OFF_ST1,
                                                       s1_bn_g, s1_bn_b, total4a);
  // ---------------- stage 2 ----------------
  for (int ci = 0; ci < nchunks; ci++) {
    int b0 = ci * chunk;
    k_tconv<<<chunk * NN * 8, 256, 0, stream>>>(A + (size_t)b0 * 508 * NC, 508, 508,
                                                ws + OFF_WT1, s2_tc1_b, HS, 510, 506);
    k_cheb<<<chunk * 506, 128, 0, stream>>>(HS, CS, ws, s2_cheb_b, 506, OFF_UP2);
    k_tconv<<<chunk * NN * 8, 256, 0, stream>>>(CS, 510, 506, ws + OFF_WT2, s2_tc2_b,
                                                A + (size_t)b0 * 508 * NC, 508, 504);
  }
  int nSlab2 = (504 + 15) / 16;
  k_bnstats<<<32 * nSlab2, 256, 0, stream>>>(A, 508, 504, ws + OFF_ST2, nSlab2);
  k_bnmean<<<(32 * NC) / 256, 256, 0, stream>>>(A, 508, 504, ws + OFF_ST2,
                                                s2_bn_g, s2_bn_b, ws + OFF_MEAN);
  k_fc<<<32, 256, 0, stream>>>(ws + OFF_MEAN, fc1_w, fc1_b, fc2_w, fc2_b, out);
}

// Round 4
// 2756.864 us; speedup vs baseline: 1.9844x; 1.5221x over previous
//
#include <hip/hip_runtime.h>
#include <math.h>

#define NN 33
#define NC 2112   // 33*64

typedef __attribute__((ext_vector_type(8))) short bfrag;
typedef __attribute__((ext_vector_type(4))) float f32x4;

// ---- ws float offsets ----
#define OFF_L    0          // 33*33 Laplacian (tgt,src)
#define OFF_L2   1100       // 33*33  2*L@L
#define OFF_UP1  2200       // 12288: cheb1 fused weights, swizzled [k4][d][4]
#define OFF_UP2  14600      // 12288: cheb2
#define OFF_WT0  26900      // 36864 floats = 73728 ushort: s1_tc2 split-bf16 MFMA layout
#define OFF_WT1  63800      // s2_tc1
#define OFF_WT2  100700     // s2_tc2
#define OFF_ST1  139400     // 66 floats: sums / sumsq per node
#define OFF_ST2  139500     // 66 floats
#define OFF_MEAN 139600     // 32*2112
#define OFF_A    207232     // big buffer: 32 * 508 * 2112 floats
#define A_ELEMS  34332672ull
#define SLAB     1077120ull // 510*2112 floats per b of scratch

__device__ inline unsigned short f2bf(float x) {
  unsigned int u = __float_as_uint(x);
  unsigned int r = (u + 0x7fffu + ((u >> 16) & 1u)) >> 16;
  return (unsigned short)r;
}
__device__ inline float bf2f(unsigned short h) {
  return __uint_as_float(((unsigned int)h) << 16);
}

// =====================================================================
// K0: build Laplacian, 2*L@L, swizzled cheb weights, split-bf16 MFMA
// tconv weights.  One block, 256 threads.
//
// tconv weight layout (per layer, 73728 ushort):
//   u = (((dt*2+ks)*12+nt)*2+sp)*512 + q*128 + nn*8 + j
//   value = split_{sp}( raw[(o*64+ci)*3+dt] ), o = nt*16+nn, ci = ks*32+q*8+j
__global__ __launch_bounds__(256) void k_prep(
    const int* __restrict__ ei,
    const float* __restrict__ cw1, const float* __restrict__ cw2,
    const float* __restrict__ tw0, const float* __restrict__ tw1,
    const float* __restrict__ tw2, float* __restrict__ ws) {
  int tid = threadIdx.x;
  float* L  = ws + OFF_L;
  float* L2 = ws + OFF_L2;
  for (int i = tid; i < NN * NN; i += 256) L[i] = 0.f;
  __syncthreads();
  if (tid == 0) {
    float deg[NN];
    for (int n = 0; n < NN; n++) deg[n] = 0.f;
    for (int e = 0; e < 64; e++) deg[ei[e]] += 1.f;
    float dinv[NN];
    for (int n = 0; n < NN; n++) dinv[n] = deg[n] > 0.f ? rsqrtf(deg[n]) : 0.f;
    for (int e = 0; e < 64; e++) {
      int s = ei[e], t = ei[64 + e];
      L[t * NN + s] -= dinv[s] * dinv[t];
    }
  }
  __syncthreads();
  for (int i = tid; i < NN * NN; i += 256) {
    int r = i / NN, c = i % NN;
    float s = 0.f;
    for (int m = 0; m < NN; m++) s += L[r * NN + m] * L[m * NN + c];
    L2[i] = 2.f * s;
  }
  // fused cheb weights:  U0 = W0 - W2 (on h), U1 = W1 (on Lh), U2 = W2 (on 2LLh)
  for (int i = tid; i < 12288; i += 256) {
    int k4 = i >> 8, d = (i >> 2) & 63, e = i & 3;
    int k = 4 * k4 + e, s = k >> 6, c = k & 63;
    float v1 = cw1[(s * 64 + c) * 64 + d];
    float v2 = cw2[(s * 64 + c) * 64 + d];
    if (s == 0) { v1 -= cw1[(128 + c) * 64 + d]; v2 -= cw2[(128 + c) * 64 + d]; }
    ws[OFF_UP1 + i] = v1;
    ws[OFF_UP2 + i] = v2;
  }
  // tconv split-bf16 MFMA weights
  unsigned short* p0 = (unsigned short*)(ws + OFF_WT0);
  unsigned short* p1 = (unsigned short*)(ws + OFF_WT1);
  unsigned short* p2 = (unsigned short*)(ws + OFF_WT2);
  for (int u = tid; u < 73728; u += 256) {
    int j  = u & 7;
    int nn_ = (u >> 3) & 15;
    int q  = (u >> 7) & 3;
    int B  = u >> 9;
    int sp = B & 1;
    int B2 = B >> 1;
    int nt = B2 % 12;
    int dk = B2 / 12;
    int ks = dk & 1;
    int dt = dk >> 1;
    int o  = nt * 16 + nn_;
    int ci = ks * 32 + q * 8 + j;
    int src = (o * 64 + ci) * 3 + dt;
    #pragma unroll
    for (int lay = 0; lay < 3; lay++) {
      const float* tw = (lay == 0) ? tw0 : (lay == 1 ? tw1 : tw2);
      unsigned short* dst = (lay == 0) ? p0 : (lay == 1 ? p1 : p2);
      float w = tw[src];
      unsigned short wh = f2bf(w);
      unsigned short v = sp ? f2bf(w - bf2f(wh)) : wh;
      dst[u] = v;
    }
  }
}

// =====================================================================
// K1: small gated tconv (Ci=3), x -> HS  (chunk slabs, stride 510 rows)
__global__ __launch_bounds__(256) void k_tconv0(
    const float* __restrict__ x, const float* __restrict__ w,
    const float* __restrict__ bias, float* __restrict__ out,
    int b0, int total) {
  __shared__ float wsm[1728];
  __shared__ float bsm[192];
  int tid = threadIdx.x;
  for (int i = tid; i < 1728; i += 256) wsm[i] = w[i];
  if (tid < 192) bsm[tid] = bias[tid];
  __syncthreads();
  int idx = blockIdx.x * 256 + tid;
  if (idx >= total) return;
  int ch = idx & 63;
  int r = idx >> 6;
  int n = r % NN; r /= NN;
  int t = r % 510;
  int bc = r / 510;
  int b = b0 + bc;
  float aP = bsm[ch], aQ = bsm[64 + ch], aR = bsm[128 + ch];
  const float* xp = x + ((size_t)(b * 512 + t) * NN + n) * 3;
  #pragma unroll
  for (int dt = 0; dt < 3; dt++) {
    float x0 = xp[dt * 99 + 0], x1 = xp[dt * 99 + 1], x2 = xp[dt * 99 + 2];
    aP += x0 * wsm[(ch * 3 + 0) * 3 + dt] + x1 * wsm[(ch * 3 + 1) * 3 + dt] + x2 * wsm[(ch * 3 + 2) * 3 + dt];
    aQ += x0 * wsm[((64 + ch) * 3 + 0) * 3 + dt] + x1 * wsm[((64 + ch) * 3 + 1) * 3 + dt] + x2 * wsm[((64 + ch) * 3 + 2) * 3 + dt];
    aR += x0 * wsm[((128 + ch) * 3 + 0) * 3 + dt] + x1 * wsm[((128 + ch) * 3 + 1) * 3 + dt] + x2 * wsm[((128 + ch) * 3 + 2) * 3 + dt];
  }
  float sg = 1.f / (1.f + __expf(-aQ));
  out[(size_t)(bc * 510 + t) * NC + n * 64 + ch] = fmaxf(aP * sg + aR, 0.f);
}

// =====================================================================
// K2: ChebConv (K=3) + bias + relu.  One (b,t) per 128-thread block.
__global__ __launch_bounds__(128) void k_cheb(
    const float* __restrict__ in, float* __restrict__ out,
    const float* __restrict__ ws, const float* __restrict__ cbias,
    int Tv, int upOff) {
  __shared__ float S[NN * 196];
  int tid = threadIdx.x;
  int bc = blockIdx.x / Tv, t = blockIdx.x % Tv;
  const float* ip = in + (size_t)(bc * 510 + t) * NC;
  for (int i4 = tid; i4 < 528; i4 += 128) {
    int n = i4 >> 4, c4 = i4 & 15;
    *(float4*)(S + n * 196 + c4 * 4) = *(const float4*)(ip + n * 64 + c4 * 4);
  }
  int c = tid & 63;
  int half = __builtin_amdgcn_readfirstlane(tid >> 6);
  __syncthreads();
  const float* Lg  = ws + OFF_L;
  const float* L2g = ws + OFF_L2;
  int nb = half * 16;
  int cnt = 16 + half;
  float t1[17], t2[17];
  #pragma unroll
  for (int i = 0; i < 17; i++) { t1[i] = 0.f; t2[i] = 0.f; }
  for (int m = 0; m < NN; m++) {
    float hv = S[m * 196 + c];
    #pragma unroll
    for (int i = 0; i < 17; i++) {
      if (i < cnt) {
        t1[i] += Lg[(nb + i) * NN + m] * hv;
        t2[i] += L2g[(nb + i) * NN + m] * hv;
      }
    }
  }
  #pragma unroll
  for (int i = 0; i < 17; i++) {
    if (i < cnt) {
      S[(nb + i) * 196 + 64 + c]  = t1[i];
      S[(nb + i) * 196 + 128 + c] = t2[i];
    }
  }
  __syncthreads();
  int dg = tid & 15, ng = (tid >> 4) & 3;
  int R = 4 + half;
  const float* Up = ws + upOff;
  float acc[5][4];
  #pragma unroll
  for (int r = 0; r < 5; r++)
    #pragma unroll
    for (int u = 0; u < 4; u++) acc[r][u] = 0.f;
  for (int k4 = 0; k4 < 48; k4++) {
    float4 up[4];
    #pragma unroll
    for (int u = 0; u < 4; u++)
      up[u] = *(const float4*)(Up + (size_t)k4 * 256 + (dg + 16 * u) * 4);
    #pragma unroll
    for (int r = 0; r < 5; r++) {
      if (r < R) {
        int n = nb + 4 * r + ng;
        if (n < NN) {
          float4 s4 = *(const float4*)(S + n * 196 + k4 * 4);
          #pragma unroll
          for (int u = 0; u < 4; u++)
            acc[r][u] += s4.x * up[u].x + s4.y * up[u].y +
                         s4.z * up[u].z + s4.w * up[u].w;
        }
      }
    }
  }
  float* op = out + (size_t)(bc * 510 + t) * NC;
  #pragma unroll
  for (int u = 0; u < 4; u++) {
    int d = dg + 16 * u;
    float bd = cbias[d];
    #pragma unroll
    for (int r = 0; r < 5; r++) {
      if (r < R) {
        int n = nb + 4 * r + ng;
        if (n < NN) op[n * 64 + d] = fmaxf(acc[r][u] + bd, 0.f);
      }
    }
  }
}

// =====================================================================
// K3 v5: gated tconv (Ci=64) via split-bf16 MFMA.
// Block = (bc, node n, 64-t tile), 256 thr (4 waves).
// GEMM: M=64 (t), N=192 (3 gates x 64), K=192 (64 ci x 3 dt).
// x ~ xh + xl, w ~ wh + wl;  acc += xh*wh + xh*wl + xl*wh  (3 MFMA/tile/kstep)
// Wave(waveM,waveN): m-tiles waveM*2+{0,1}, n-tiles waveN*6+{0..5}.
// LDS: Ah/Al 66 rows x 72 bf16 (pad: 4-bank rotate), B per-dt 48KB frag-blocks;
//      C (64x192 f32) overlays B for the gating epilogue.
__global__ __launch_bounds__(256) void k_tconv(
    const float* __restrict__ in, int inStride, int Tin,
    const unsigned short* __restrict__ wsp, const float* __restrict__ bias,
    float* __restrict__ out, int outStride, int Tout) {
  __shared__ __attribute__((aligned(16))) char lds[68160];
  unsigned short* Ah = (unsigned short*)lds;          // 66*72 = 4752
  unsigned short* Al = Ah + 4752;                     // 4752
  unsigned short* Bs = (unsigned short*)(lds + 19008);// 24576 ushort = 48 KB
  float* Cs = (float*)(lds + 19008);                  // 64*192 f32 = 48 KB

  int tid = threadIdx.x;
  int ntt = (Tout + 63) >> 6;
  int tpb = NN * ntt;
  int bc = blockIdx.x / tpb, r = blockIdx.x % tpb;
  int n = r / ntt, tt = r % ntt;
  int t0 = tt << 6;
  const float* ip = in + (size_t)bc * inStride * NC + n * 64;

  // ---- stage A (fp32 -> split bf16) ----
  for (int i = tid; i < 66 * 16; i += 256) {
    int row = i >> 4, c4 = i & 15;
    float4 v = make_float4(0.f, 0.f, 0.f, 0.f);
    if (t0 + row < Tin) v = *(const float4*)(ip + (size_t)(t0 + row) * NC + c4 * 4);
    unsigned short h0 = f2bf(v.x), h1 = f2bf(v.y), h2 = f2bf(v.z), h3 = f2bf(v.w);
    unsigned short l0 = f2bf(v.x - bf2f(h0)), l1 = f2bf(v.y - bf2f(h1));
    unsigned short l2 = f2bf(v.z - bf2f(h2)), l3 = f2bf(v.w - bf2f(h3));
    uint2 ph, pl;
    ph.x = (unsigned)h0 | ((unsigned)h1 << 16); ph.y = (unsigned)h2 | ((unsigned)h3 << 16);
    pl.x = (unsigned)l0 | ((unsigned)l1 << 16); pl.y = (unsigned)l2 | ((unsigned)l3 << 16);
    *(uint2*)(Ah + row * 72 + c4 * 4) = ph;
    *(uint2*)(Al + row * 72 + c4 * 4) = pl;
  }

  int lane = tid & 63;
  int wv = tid >> 6;
  int waveM = wv >> 1, waveN = wv & 1;
  int m15 = lane & 15, q = lane >> 4;

  f32x4 acc[2][6];
  #pragma unroll
  for (int mi = 0; mi < 2; mi++)
    #pragma unroll
    for (int ni = 0; ni < 6; ni++) acc[mi][ni] = (f32x4){0.f, 0.f, 0.f, 0.f};

  for (int dt = 0; dt < 3; dt++) {
    __syncthreads();
    const uint4* src = (const uint4*)(wsp + (size_t)dt * 24576);
    uint4* dstB = (uint4*)Bs;
    for (int i = tid; i < 3072; i += 256) dstB[i] = src[i];
    __syncthreads();
    #pragma unroll
    for (int ks = 0; ks < 2; ks++) {
      bfrag ah[2], al[2];
      #pragma unroll
      for (int mi = 0; mi < 2; mi++) {
        int row = waveM * 32 + mi * 16 + m15 + dt;
        int off = row * 72 + ks * 32 + q * 8;
        ah[mi] = *(const bfrag*)(Ah + off);
        al[mi] = *(const bfrag*)(Al + off);
      }
      bfrag bh[6], bl[6];
      #pragma unroll
      for (int ni = 0; ni < 6; ni++) {
        int nt = waveN * 6 + ni;
        const unsigned short* bp = Bs + ((ks * 12 + nt) * 2) * 512 + lane * 8;
        bh[ni] = *(const bfrag*)bp;
        bl[ni] = *(const bfrag*)(bp + 512);
      }
      #pragma unroll
      for (int mi = 0; mi < 2; mi++)
        #pragma unroll
        for (int ni = 0; ni < 6; ni++) {
          acc[mi][ni] = __builtin_amdgcn_mfma_f32_16x16x32_bf16(ah[mi], bh[ni], acc[mi][ni], 0, 0, 0);
          acc[mi][ni] = __builtin_amdgcn_mfma_f32_16x16x32_bf16(ah[mi], bl[ni], acc[mi][ni], 0, 0, 0);
          acc[mi][ni] = __builtin_amdgcn_mfma_f32_16x16x32_bf16(al[mi], bh[ni], acc[mi][ni], 0, 0, 0);
        }
    }
  }

  // ---- epilogue: C tiles -> LDS, then gate + relu + store ----
  __syncthreads();
  #pragma unroll
  for (int mi = 0; mi < 2; mi++)
    #pragma unroll
    for (int ni = 0; ni < 6; ni++) {
      int o = (waveN * 6 + ni) * 16 + m15;
      int mb = waveM * 32 + mi * 16 + q * 4;
      #pragma unroll
      for (int rr = 0; rr < 4; rr++)
        Cs[(mb + rr) * 192 + o] = acc[mi][ni][rr];
    }
  __syncthreads();
  int ch = tid & 63;
  float b0v = bias[ch], b1v = bias[64 + ch], b2v = bias[128 + ch];
  for (int m = tid >> 6; m < 64; m += 4) {
    int t = t0 + m;
    if (t < Tout) {
      float P = Cs[m * 192 + ch] + b0v;
      float Q = Cs[m * 192 + 64 + ch] + b1v;
      float Rv = Cs[m * 192 + 128 + ch] + b2v;
      float sg = 1.f / (1.f + __expf(-Q));
      out[(size_t)(bc * outStride + t) * NC + n * 64 + ch] = fmaxf(P * sg + Rv, 0.f);
    }
  }
}

// =====================================================================
// K4: BN stats (sum, sumsq per node) over full batch, into ws via atomics.
__global__ __launch_bounds__(256) void k_bnstats(
    const float* __restrict__ A, int stride, int Tv,
    float* __restrict__ st, int nSlab) {
  __shared__ float ls[66];
  int tid = threadIdx.x;
  if (tid < 66) ls[tid] = 0.f;
  __syncthreads();
  int b = blockIdx.x / nSlab, sl = blockIdx.x % nSlab;
  int t0 = sl * 16;
  int tmax = min(16, Tv - t0);
  for (int p = tid; p < NC; p += 256) {
    int n = p >> 6;
    float s = 0.f, q = 0.f;
    for (int dt = 0; dt < tmax; dt++) {
      float v = A[(size_t)(b * stride + t0 + dt) * NC + p];
      s += v; q += v * v;
    }
    atomicAdd(&ls[n], s);
    atomicAdd(&ls[33 + n], q);
  }
  __syncthreads();
  if (tid < 66) atomicAdd(&st[tid], ls[tid]);
}

// K5: BN apply + relu, in place (stage 1)
__global__ __launch_bounds__(256) void k_bnapply(
    float* __restrict__ A, int stride, int Tv,
    const float* __restrict__ st, const float* __restrict__ gg,
    const float* __restrict__ bb, int total4) {
  int idx = blockIdx.x * 256 + threadIdx.x;
  if (idx >= total4) return;
  int i16 = idx & 15;
  int n = (idx >> 4) % NN;
  int rest = (idx >> 4) / NN;
  int t = rest % Tv, b = rest / Tv;
  float cnt = (float)(32 * Tv * 64);
  float mean = st[n] / cnt;
  float var = st[33 + n] / cnt - mean * mean;
  float sc = rsqrtf(var + 1e-5f) * gg[n];
  float sh = bb[n] - mean * sc;
  float4* p = (float4*)(A + (size_t)(b * stride + t) * NC + n * 64 + i16 * 4);
  float4 v = *p;
  v.x = fmaxf(v.x * sc + sh, 0.f);
  v.y = fmaxf(v.y * sc + sh, 0.f);
  v.z = fmaxf(v.z * sc + sh, 0.f);
  v.w = fmaxf(v.w * sc + sh, 0.f);
  *p = v;
}

// K5b: BN apply + relu + mean over T (stage 2), no materialization.
__global__ __launch_bounds__(256) void k_bnmean(
    const float* __restrict__ A, int stride, int Tv,
    const float* __restrict__ st, const float* __restrict__ gg,
    const float* __restrict__ bb, float* __restrict__ mout) {
  int idx = blockIdx.x * 256 + threadIdx.x;   // 32*2112
  int p = idx % NC, b = idx / NC;
  int n = p >> 6;
  float cnt = (float)(32 * Tv * 64);
  float mean = st[n] / cnt;
  float var = st[33 + n] / cnt - mean * mean;
  float sc = rsqrtf(var + 1e-5f) * gg[n];
  float sh = bb[n] - mean * sc;
  float acc = 0.f;
  const float* ap = A + (size_t)b * stride * NC + p;
  for (int t = 0; t < Tv; t += 4) {
    acc += fmaxf(ap[(size_t)t * NC] * sc + sh, 0.f)
         + fmaxf(ap[(size_t)(t + 1) * NC] * sc + sh, 0.f)
         + fmaxf(ap[(size_t)(t + 2) * NC] * sc + sh, 0.f)
         + fmaxf(ap[(size_t)(t + 3) * NC] * sc + sh, 0.f);
  }
  mout[idx] = acc / (float)Tv;
}

// K6: classifier head.  One block per batch sample.
__global__ __launch_bounds__(256) void k_fc(
    const float* __restrict__ meanb, const float* __restrict__ w1,
    const float* __restrict__ b1, const float* __restrict__ w2,
    const float* __restrict__ b2, float* __restrict__ out) {
  __shared__ float m[NC];
  __shared__ float h[256];
  int tid = threadIdx.x, b = blockIdx.x;
  for (int i4 = tid; i4 < 528; i4 += 256)
    *(float4*)(m + i4 * 4) = *(const float4*)(meanb + b * NC + i4 * 4);
  __syncthreads();
  float acc = b1[tid];
  for (int k = 0; k < NC; k += 8) {
    #pragma unroll
    for (int u = 0; u < 8; u++) acc += m[k + u] * w1[(k + u) * 256 + tid];
  }
  h[tid] = fmaxf(acc, 0.f);
  __syncthreads();
  if (tid < 10) {
    float a = b2[tid];
    for (int k = 0; k < 256; k++) a += h[k] * w2[k * 10 + tid];
    out[b * 10 + tid] = a;
  }
}

// =====================================================================
extern "C" void kernel_launch(void* const* d_in, const int* in_sizes, int n_in,
                              void* d_out, int out_size, void* d_ws, size_t ws_size,
                              hipStream_t stream) {
  const float* x        = (const float*)d_in[0];
  const int*   ei       = (const int*)d_in[1];
  const float* s1_tc1_w = (const float*)d_in[2];
  const float* s1_tc1_b = (const float*)d_in[3];
  const float* s1_cheb_w= (const float*)d_in[4];
  const float* s1_cheb_b= (const float*)d_in[5];
  const float* s1_tc2_w = (const float*)d_in[6];
  const float* s1_tc2_b = (const float*)d_in[7];
  const float* s1_bn_g  = (const float*)d_in[8];
  const float* s1_bn_b  = (const float*)d_in[9];
  const float* s2_tc1_w = (const float*)d_in[10];
  const float* s2_tc1_b = (const float*)d_in[11];
  const float* s2_cheb_w= (const float*)d_in[12];
  const float* s2_cheb_b= (const float*)d_in[13];
  const float* s2_tc2_w = (const float*)d_in[14];
  const float* s2_tc2_b = (const float*)d_in[15];
  const float* s2_bn_g  = (const float*)d_in[16];
  const float* s2_bn_b  = (const float*)d_in[17];
  const float* fc1_w    = (const float*)d_in[18];
  const float* fc1_b    = (const float*)d_in[19];
  const float* fc2_w    = (const float*)d_in[20];
  const float* fc2_b    = (const float*)d_in[21];
  float* ws  = (float*)d_ws;
  float* out = (float*)d_out;

  int chunk = 8;
  while (chunk > 1 &&
         ((size_t)OFF_A + A_ELEMS + (size_t)chunk * SLAB * 2) * 4 > ws_size)
    chunk >>= 1;
  float* A  = ws + OFF_A;
  float* HS = A + A_ELEMS;
  float* CS = HS + (size_t)chunk * SLAB;

  hipMemsetAsync(ws + OFF_ST1, 0, 200 * sizeof(float), stream);
  k_prep<<<1, 256, 0, stream>>>(ei, s1_cheb_w, s2_cheb_w,
                                s1_tc2_w, s2_tc1_w, s2_tc2_w, ws);

  const unsigned short* wt0 = (const unsigned short*)(ws + OFF_WT0);
  const unsigned short* wt1 = (const unsigned short*)(ws + OFF_WT1);
  const unsigned short* wt2 = (const unsigned short*)(ws + OFF_WT2);

  int nchunks = 32 / chunk;
  // ---------------- stage 1 ----------------
  for (int ci = 0; ci < nchunks; ci++) {
    int b0 = ci * chunk;
    int total0 = chunk * 510 * NC;
    k_tconv0<<<(total0 + 255) / 256, 256, 0, stream>>>(x, s1_tc1_w, s1_tc1_b,
                                                       HS, b0, total0);
    k_cheb<<<chunk * 510, 128, 0, stream>>>(HS, CS, ws, s1_cheb_b, 510, OFF_UP1);
    k_tconv<<<chunk * NN * 8, 256, 0, stream>>>(CS, 510, 510, wt0, s1_tc2_b,
                                                A + (size_t)b0 * 508 * NC, 508, 508);
  }
  int nSlab1 = (508 + 15) / 16;
  k_bnstats<<<32 * nSlab1, 256, 0, stream>>>(A, 508, 508, ws + OFF_ST1, nSlab1);
  int total4a = 32 * 508 * 528;
  k_bnapply<<<(total4a + 255) / 256, 256, 0, stream>>>(A, 508, 508, ws + OFF_ST1,
                                                       s1_bn_g, s1_bn_b, total4a);
  // ---------------- stage 2 ----------------
  for (int ci = 0; ci < nchunks; ci++) {
    int b0 = ci * chunk;
    k_tconv<<<chunk * NN * 8, 256, 0, stream>>>(A + (size_t)b0 * 508 * NC, 508, 508,
                                                wt1, s2_tc1_b, HS, 510, 506);
    k_cheb<<<chunk * 506, 128, 0, stream>>>(HS, CS, ws, s2_cheb_b, 506, OFF_UP2);
    k_tconv<<<chunk * NN * 8, 256, 0, stream>>>(CS, 510, 506, wt2, s2_tc2_b,
                                                A + (size_t)b0 * 508 * NC, 508, 504);
  }
  int nSlab2 = (504 + 15) / 16;
  k_bnstats<<<32 * nSlab2, 256, 0, stream>>>(A, 508, 504, ws + OFF_ST2, nSlab2);
  k_bnmean<<<(32 * NC) / 256, 256, 0, stream>>>(A, 508, 504, ws + OFF_ST2,
                                                s2_bn_g, s2_bn_b, ws + OFF_MEAN);
  k_fc<<<32, 256, 0, stream>>>(ws + OFF_MEAN, fc1_w, fc1_b, fc2_w, fc2_b, out);
}

// Round 5
// 2110.521 us; speedup vs baseline: 2.5921x; 1.3062x over previous
//
#include <hip/hip_runtime.h>
#include <math.h>

#define NN 33
#define NC 2112   // 33*64

typedef __attribute__((ext_vector_type(8))) short bfrag;
typedef __attribute__((ext_vector_type(4))) float f32x4;

// ---- ws float offsets ----
#define OFF_LT   0          // 33*68: L^T column-doubled  LTd[m][nn]=L[nn%33][m]
#define OFF_L2T  2244       // 33*68: (2*L@L)^T column-doubled
#define OFF_UP1  4488       // 24576 ushort: cheb1 fused U, split-bf16 B-frag blocks
#define OFF_UP2  16776      // cheb2
#define OFF_WT0  29064      // 73728 ushort: s1_tc2 split-bf16 MFMA layout
#define OFF_WT1  65928      // s2_tc1
#define OFF_WT2  102792     // s2_tc2
#define OFF_ST1  139656     // 66 floats
#define OFF_ST2  139722     // 66 floats
#define OFF_MEAN 139856     // 32*2112
#define OFF_A    207440     // big buffer: 32 * 508 * 2112 floats
#define A_ELEMS  34332672ull
#define SLAB     1077120ull // 510*2112 floats per b of scratch

__device__ inline unsigned short f2bf(float x) {
  unsigned int u = __float_as_uint(x);
  unsigned int r = (u + 0x7fffu + ((u >> 16) & 1u)) >> 16;
  return (unsigned short)r;
}
__device__ inline float bf2f(unsigned short h) {
  return __uint_as_float(((unsigned int)h) << 16);
}

// =====================================================================
// K0: build LTd/L2Td, fused cheb U in split-bf16 B-frag layout, split-bf16
// tconv weights.  One block, 256 threads.
__global__ __launch_bounds__(256) void k_prep(
    const int* __restrict__ ei,
    const float* __restrict__ cw1, const float* __restrict__ cw2,
    const float* __restrict__ tw0, const float* __restrict__ tw1,
    const float* __restrict__ tw2, float* __restrict__ ws) {
  __shared__ float Lsm[1089];
  __shared__ float L2sm[1089];
  int tid = threadIdx.x;
  for (int i = tid; i < 1089; i += 256) Lsm[i] = 0.f;
  __syncthreads();
  if (tid == 0) {
    float deg[NN];
    for (int n = 0; n < NN; n++) deg[n] = 0.f;
    for (int e = 0; e < 64; e++) deg[ei[e]] += 1.f;
    float dinv[NN];
    for (int n = 0; n < NN; n++) dinv[n] = deg[n] > 0.f ? rsqrtf(deg[n]) : 0.f;
    for (int e = 0; e < 64; e++) {
      int s = ei[e], t = ei[64 + e];
      Lsm[t * NN + s] -= dinv[s] * dinv[t];
    }
  }
  __syncthreads();
  for (int i = tid; i < 1089; i += 256) {
    int r = i / NN, c = i % NN;
    float s = 0.f;
    for (int m = 0; m < NN; m++) s += Lsm[r * NN + m] * Lsm[m * NN + c];
    L2sm[i] = 2.f * s;
  }
  __syncthreads();
  // transposed + column-doubled
  for (int i = tid; i < 33 * 66; i += 256) {
    int m = i / 66, nn = i % 66;
    int n33 = nn < 33 ? nn : nn - 33;
    ws[OFF_LT + m * 68 + nn]  = Lsm[n33 * NN + m];
    ws[OFF_L2T + m * 68 + nn] = L2sm[n33 * NN + m];
  }
  // fused cheb U (U0 = W0 - W2 on h, U1 = W1 on Lh, U2 = W2 on 2LLh)
  // B-frag blocks: addr = (ks*4+nt)*1024 + sp*512 + q*128 + nn*8 + j
  //   value = split_sp( Ufused[k=ks*32+q*8+j][d=nt*16+nn] )
  unsigned short* u1 = (unsigned short*)(ws + OFF_UP1);
  unsigned short* u2 = (unsigned short*)(ws + OFF_UP2);
  for (int u = tid; u < 24576; u += 256) {
    int j = u & 7;
    int nn = (u >> 3) & 15;
    int q = (u >> 7) & 3;
    int sp = (u >> 9) & 1;
    int blk = u >> 10;
    int nt = blk & 3;
    int ks = blk >> 2;
    int k = ks * 32 + q * 8 + j;
    int d = nt * 16 + nn;
    int s = k >> 6, cc = k & 63;
    float v1 = cw1[(s * 64 + cc) * 64 + d];
    float v2 = cw2[(s * 64 + cc) * 64 + d];
    if (s == 0) { v1 -= cw1[(128 + cc) * 64 + d]; v2 -= cw2[(128 + cc) * 64 + d]; }
    unsigned short h1 = f2bf(v1);
    u1[u] = sp ? f2bf(v1 - bf2f(h1)) : h1;
    unsigned short h2 = f2bf(v2);
    u2[u] = sp ? f2bf(v2 - bf2f(h2)) : h2;
  }
  // tconv split-bf16 MFMA weights (unchanged layout from R4)
  unsigned short* p0 = (unsigned short*)(ws + OFF_WT0);
  unsigned short* p1 = (unsigned short*)(ws + OFF_WT1);
  unsigned short* p2 = (unsigned short*)(ws + OFF_WT2);
  for (int u = tid; u < 73728; u += 256) {
    int j  = u & 7;
    int nn_ = (u >> 3) & 15;
    int q  = (u >> 7) & 3;
    int B  = u >> 9;
    int sp = B & 1;
    int B2 = B >> 1;
    int nt = B2 % 12;
    int dk = B2 / 12;
    int ks = dk & 1;
    int dt = dk >> 1;
    int o  = nt * 16 + nn_;
    int ci = ks * 32 + q * 8 + j;
    int src = (o * 64 + ci) * 3 + dt;
    #pragma unroll
    for (int lay = 0; lay < 3; lay++) {
      const float* tw = (lay == 0) ? tw0 : (lay == 1 ? tw1 : tw2);
      unsigned short* dst = (lay == 0) ? p0 : (lay == 1 ? p1 : p2);
      float w = tw[src];
      unsigned short wh = f2bf(w);
      dst[u] = sp ? f2bf(w - bf2f(wh)) : wh;
    }
  }
}

// =====================================================================
// K1: small gated tconv (Ci=3), x -> HS  (chunk slabs, stride 510 rows)
__global__ __launch_bounds__(256) void k_tconv0(
    const float* __restrict__ x, const float* __restrict__ w,
    const float* __restrict__ bias, float* __restrict__ out,
    int b0, int total) {
  __shared__ float wsm[1728];
  __shared__ float bsm[192];
  int tid = threadIdx.x;
  for (int i = tid; i < 1728; i += 256) wsm[i] = w[i];
  if (tid < 192) bsm[tid] = bias[tid];
  __syncthreads();
  int idx = blockIdx.x * 256 + tid;
  if (idx >= total) return;
  int ch = idx & 63;
  int r = idx >> 6;
  int n = r % NN; r /= NN;
  int t = r % 510;
  int bc = r / 510;
  int b = b0 + bc;
  float aP = bsm[ch], aQ = bsm[64 + ch], aR = bsm[128 + ch];
  const float* xp = x + ((size_t)(b * 512 + t) * NN + n) * 3;
  #pragma unroll
  for (int dt = 0; dt < 3; dt++) {
    float x0 = xp[dt * 99 + 0], x1 = xp[dt * 99 + 1], x2 = xp[dt * 99 + 2];
    aP += x0 * wsm[(ch * 3 + 0) * 3 + dt] + x1 * wsm[(ch * 3 + 1) * 3 + dt] + x2 * wsm[(ch * 3 + 2) * 3 + dt];
    aQ += x0 * wsm[((64 + ch) * 3 + 0) * 3 + dt] + x1 * wsm[((64 + ch) * 3 + 1) * 3 + dt] + x2 * wsm[((64 + ch) * 3 + 2) * 3 + dt];
    aR += x0 * wsm[((128 + ch) * 3 + 0) * 3 + dt] + x1 * wsm[((128 + ch) * 3 + 1) * 3 + dt] + x2 * wsm[((128 + ch) * 3 + 2) * 3 + dt];
  }
  float sg = 1.f / (1.f + __expf(-aQ));
  out[(size_t)(bc * 510 + t) * NC + n * 64 + ch] = fmaxf(aP * sg + aR, 0.f);
}

// =====================================================================
// K2 v3: fused ChebConv: prop (VALU, scalar-batched L loads) + GEMM (MFMA).
// Rows R = bt*33+n flattened; h is contiguous at in + 64*R.
// Block = 64 rows, 256 thr (4 waves, wave g owns rows g*16..g*16+15).
// LDS: hbuf 3 bt-slabs fp32 (25.3 KB) + Ah/Al 64x200 bf16 (51.2 KB).
__global__ __launch_bounds__(256) void k_chebmm(
    const float* __restrict__ in, const unsigned short* __restrict__ Uf,
    const float* __restrict__ cbias, float* __restrict__ out,
    const float* __restrict__ ws, int totalRows) {
  __shared__ __attribute__((aligned(16))) char lds[76544];
  float* hbuf = (float*)lds;                       // 3*2112 fp32
  unsigned short* Ah = (unsigned short*)(lds + 25344); // 64*200
  unsigned short* Al = Ah + 12800;                 // 64*200

  int tid = threadIdx.x;
  int R0 = blockIdx.x * 64;
  int bt0 = R0 / 33;
  int btTotal = totalRows / 33;

  // ---- stage h for the <=3 spanned bt's ----
  for (int i = tid; i < 1584; i += 256) {
    int lb = i / 528, r2 = i % 528;
    int m = r2 >> 4, cc = r2 & 15;
    int bt = bt0 + lb;
    float4 v = make_float4(0.f, 0.f, 0.f, 0.f);
    if (bt < btTotal) v = *(const float4*)(in + (size_t)bt * NC + m * 64 + cc * 4);
    *(float4*)(hbuf + lb * NC + m * 64 + cc * 4) = v;
  }
  __syncthreads();

  int c = tid & 63;
  int g = __builtin_amdgcn_readfirstlane(tid >> 6);
  int Rg = R0 + g * 16;
  int btg = Rg / 33;
  int n0 = Rg - btg * 33;          // wave-uniform
  int lb0 = btg - bt0;
  int wrap = 33 - n0;              // rr >= wrap -> next bt
  int lbB = lb0 + 1 > 2 ? 2 : lb0 + 1;

  const float* lt  = ws + OFF_LT;
  const float* l2t = ws + OFF_L2T;
  float z1[16], z2[16];
  #pragma unroll
  for (int rr = 0; rr < 16; rr++) { z1[rr] = 0.f; z2[rr] = 0.f; }
  for (int m = 0; m < NN; m++) {
    float hvA = hbuf[lb0 * NC + m * 64 + c];
    float hvB = hbuf[lbB * NC + m * 64 + c];
    const float* ltm  = lt + m * 68 + n0;
    const float* l2tm = l2t + m * 68 + n0;
    #pragma unroll
    for (int rr = 0; rr < 16; rr++) {
      float hv = (rr < wrap) ? hvA : hvB;
      z1[rr] += ltm[rr] * hv;
      z2[rr] += l2tm[rr] * hv;
    }
  }
  // pack h / Z1 / Z2 split-bf16 into Ah/Al (stride 200, conflict-free)
  #pragma unroll
  for (int rr = 0; rr < 16; rr++) {
    int n = n0 + rr, lb = lb0;
    if (n >= 33) { n -= 33; lb++; }
    int r = g * 16 + rr;
    float hcv = hbuf[lb * NC + n * 64 + c];
    unsigned short hh = f2bf(hcv);
    Ah[r * 200 + c] = hh;
    Al[r * 200 + c] = f2bf(hcv - bf2f(hh));
    unsigned short zh1 = f2bf(z1[rr]);
    Ah[r * 200 + 64 + c] = zh1;
    Al[r * 200 + 64 + c] = f2bf(z1[rr] - bf2f(zh1));
    unsigned short zh2 = f2bf(z2[rr]);
    Ah[r * 200 + 128 + c] = zh2;
    Al[r * 200 + 128 + c] = f2bf(z2[rr] - bf2f(zh2));
  }
  __syncthreads();

  // ---- MFMA: out[r][d] = sum_k A[r][k] U[k][d], K=192, N=64 ----
  int lane = tid & 63;
  int m15 = lane & 15, q = lane >> 4;
  f32x4 acc[4];
  #pragma unroll
  for (int nt = 0; nt < 4; nt++) acc[nt] = (f32x4){0.f, 0.f, 0.f, 0.f};
  #pragma unroll
  for (int ks = 0; ks < 6; ks++) {
    int aoff = (g * 16 + m15) * 200 + ks * 32 + q * 8;
    bfrag ah = *(const bfrag*)(Ah + aoff);
    bfrag al = *(const bfrag*)(Al + aoff);
    #pragma unroll
    for (int nt = 0; nt < 4; nt++) {
      const unsigned short* bp = Uf + (ks * 4 + nt) * 1024 + lane * 8;
      bfrag bh = *(const bfrag*)bp;
      bfrag bl = *(const bfrag*)(bp + 512);
      acc[nt] = __builtin_amdgcn_mfma_f32_16x16x32_bf16(ah, bh, acc[nt], 0, 0, 0);
      acc[nt] = __builtin_amdgcn_mfma_f32_16x16x32_bf16(ah, bl, acc[nt], 0, 0, 0);
      acc[nt] = __builtin_amdgcn_mfma_f32_16x16x32_bf16(al, bh, acc[nt], 0, 0, 0);
    }
  }
  // ---- epilogue: bias + relu, direct stores ----
  #pragma unroll
  for (int nt = 0; nt < 4; nt++) {
    int d = nt * 16 + m15;
    float bd = cbias[d];
    #pragma unroll
    for (int rr = 0; rr < 4; rr++) {
      int R = R0 + g * 16 + q * 4 + rr;
      if (R < totalRows)
        out[(size_t)R * 64 + d] = fmaxf(acc[nt][rr] + bd, 0.f);
    }
  }
}

// =====================================================================
// K3: gated tconv (Ci=64) via split-bf16 MFMA (verified R4).
__global__ __launch_bounds__(256) void k_tconv(
    const float* __restrict__ in, int inStride, int Tin,
    const unsigned short* __restrict__ wsp, const float* __restrict__ bias,
    float* __restrict__ out, int outStride, int Tout) {
  __shared__ __attribute__((aligned(16))) char lds[68160];
  unsigned short* Ah = (unsigned short*)lds;
  unsigned short* Al = Ah + 4752;
  unsigned short* Bs = (unsigned short*)(lds + 19008);
  float* Cs = (float*)(lds + 19008);

  int tid = threadIdx.x;
  int ntt = (Tout + 63) >> 6;
  int tpb = NN * ntt;
  int bc = blockIdx.x / tpb, r = blockIdx.x % tpb;
  int n = r / ntt, tt = r % ntt;
  int t0 = tt << 6;
  const float* ip = in + (size_t)bc * inStride * NC + n * 64;

  for (int i = tid; i < 66 * 16; i += 256) {
    int row = i >> 4, c4 = i & 15;
    float4 v = make_float4(0.f, 0.f, 0.f, 0.f);
    if (t0 + row < Tin) v = *(const float4*)(ip + (size_t)(t0 + row) * NC + c4 * 4);
    unsigned short h0 = f2bf(v.x), h1 = f2bf(v.y), h2 = f2bf(v.z), h3 = f2bf(v.w);
    unsigned short l0 = f2bf(v.x - bf2f(h0)), l1 = f2bf(v.y - bf2f(h1));
    unsigned short l2 = f2bf(v.z - bf2f(h2)), l3 = f2bf(v.w - bf2f(h3));
    uint2 ph, pl;
    ph.x = (unsigned)h0 | ((unsigned)h1 << 16); ph.y = (unsigned)h2 | ((unsigned)h3 << 16);
    pl.x = (unsigned)l0 | ((unsigned)l1 << 16); pl.y = (unsigned)l2 | ((unsigned)l3 << 16);
    *(uint2*)(Ah + row * 72 + c4 * 4) = ph;
    *(uint2*)(Al + row * 72 + c4 * 4) = pl;
  }

  int lane = tid & 63;
  int wv = tid >> 6;
  int waveM = wv >> 1, waveN = wv & 1;
  int m15 = lane & 15, q = lane >> 4;

  f32x4 acc[2][6];
  #pragma unroll
  for (int mi = 0; mi < 2; mi++)
    #pragma unroll
    for (int ni = 0; ni < 6; ni++) acc[mi][ni] = (f32x4){0.f, 0.f, 0.f, 0.f};

  for (int dt = 0; dt < 3; dt++) {
    __syncthreads();
    const uint4* src = (const uint4*)(wsp + (size_t)dt * 24576);
    uint4* dstB = (uint4*)Bs;
    for (int i = tid; i < 3072; i += 256) dstB[i] = src[i];
    __syncthreads();
    #pragma unroll
    for (int ks = 0; ks < 2; ks++) {
      bfrag ah[2], al[2];
      #pragma unroll
      for (int mi = 0; mi < 2; mi++) {
        int row = waveM * 32 + mi * 16 + m15 + dt;
        int off = row * 72 + ks * 32 + q * 8;
        ah[mi] = *(const bfrag*)(Ah + off);
        al[mi] = *(const bfrag*)(Al + off);
      }
      bfrag bh[6], bl[6];
      #pragma unroll
      for (int ni = 0; ni < 6; ni++) {
        int nt = waveN * 6 + ni;
        const unsigned short* bp = Bs + ((ks * 12 + nt) * 2) * 512 + lane * 8;
        bh[ni] = *(const bfrag*)bp;
        bl[ni] = *(const bfrag*)(bp + 512);
      }
      #pragma unroll
      for (int mi = 0; mi < 2; mi++)
        #pragma unroll
        for (int ni = 0; ni < 6; ni++) {
          acc[mi][ni] = __builtin_amdgcn_mfma_f32_16x16x32_bf16(ah[mi], bh[ni], acc[mi][ni], 0, 0, 0);
          acc[mi][ni] = __builtin_amdgcn_mfma_f32_16x16x32_bf16(ah[mi], bl[ni], acc[mi][ni], 0, 0, 0);
          acc[mi][ni] = __builtin_amdgcn_mfma_f32_16x16x32_bf16(al[mi], bh[ni], acc[mi][ni], 0, 0, 0);
        }
    }
  }

  __syncthreads();
  #pragma unroll
  for (int mi = 0; mi < 2; mi++)
    #pragma unroll
    for (int ni = 0; ni < 6; ni++) {
      int o = (waveN * 6 + ni) * 16 + m15;
      int mb = waveM * 32 + mi * 16 + q * 4;
      #pragma unroll
      for (int rr = 0; rr < 4; rr++)
        Cs[(mb + rr) * 192 + o] = acc[mi][ni][rr];
    }
  __syncthreads();
  int ch = tid & 63;
  float b0v = bias[ch], b1v = bias[64 + ch], b2v = bias[128 + ch];
  for (int m = tid >> 6; m < 64; m += 4) {
    int t = t0 + m;
    if (t < Tout) {
      float P = Cs[m * 192 + ch] + b0v;
      float Q = Cs[m * 192 + 64 + ch] + b1v;
      float Rv = Cs[m * 192 + 128 + ch] + b2v;
      float sg = 1.f / (1.f + __expf(-Q));
      out[(size_t)(bc * outStride + t) * NC + n * 64 + ch] = fmaxf(P * sg + Rv, 0.f);
    }
  }
}

// =====================================================================
// K4: BN stats (sum, sumsq per node) over full batch, into ws via atomics.
__global__ __launch_bounds__(256) void k_bnstats(
    const float* __restrict__ A, int stride, int Tv,
    float* __restrict__ st, int nSlab) {
  __shared__ float ls[66];
  int tid = threadIdx.x;
  if (tid < 66) ls[tid] = 0.f;
  __syncthreads();
  int b = blockIdx.x / nSlab, sl = blockIdx.x % nSlab;
  int t0 = sl * 16;
  int tmax = min(16, Tv - t0);
  for (int p = tid; p < NC; p += 256) {
    int n = p >> 6;
    float s = 0.f, q = 0.f;
    for (int dt = 0; dt < tmax; dt++) {
      float v = A[(size_t)(b * stride + t0 + dt) * NC + p];
      s += v; q += v * v;
    }
    atomicAdd(&ls[n], s);
    atomicAdd(&ls[33 + n], q);
  }
  __syncthreads();
  if (tid < 66) atomicAdd(&st[tid], ls[tid]);
}

// K5: BN apply + relu, in place (stage 1)
__global__ __launch_bounds__(256) void k_bnapply(
    float* __restrict__ A, int stride, int Tv,
    const float* __restrict__ st, const float* __restrict__ gg,
    const float* __restrict__ bb, int total4) {
  int idx = blockIdx.x * 256 + threadIdx.x;
  if (idx >= total4) return;
  int i16 = idx & 15;
  int n = (idx >> 4) % NN;
  int rest = (idx >> 4) / NN;
  int t = rest % Tv, b = rest / Tv;
  float cnt = (float)(32 * Tv * 64);
  float mean = st[n] / cnt;
  float var = st[33 + n] / cnt - mean * mean;
  float sc = rsqrtf(var + 1e-5f) * gg[n];
  float sh = bb[n] - mean * sc;
  float4* p = (float4*)(A + (size_t)(b * stride + t) * NC + n * 64 + i16 * 4);
  float4 v = *p;
  v.x = fmaxf(v.x * sc + sh, 0.f);
  v.y = fmaxf(v.y * sc + sh, 0.f);
  v.z = fmaxf(v.z * sc + sh, 0.f);
  v.w = fmaxf(v.w * sc + sh, 0.f);
  *p = v;
}

// K5b: BN apply + relu + mean over T (stage 2), no materialization.
__global__ __launch_bounds__(256) void k_bnmean(
    const float* __restrict__ A, int stride, int Tv,
    const float* __restrict__ st, const float* __restrict__ gg,
    const float* __restrict__ bb, float* __restrict__ mout) {
  int idx = blockIdx.x * 256 + threadIdx.x;   // 32*2112
  int p = idx % NC, b = idx / NC;
  int n = p >> 6;
  float cnt = (float)(32 * Tv * 64);
  float mean = st[n] / cnt;
  float var = st[33 + n] / cnt - mean * mean;
  float sc = rsqrtf(var + 1e-5f) * gg[n];
  float sh = bb[n] - mean * sc;
  float acc = 0.f;
  const float* ap = A + (size_t)b * stride * NC + p;
  for (int t = 0; t < Tv; t += 4) {
    acc += fmaxf(ap[(size_t)t * NC] * sc + sh, 0.f)
         + fmaxf(ap[(size_t)(t + 1) * NC] * sc + sh, 0.f)
         + fmaxf(ap[(size_t)(t + 2) * NC] * sc + sh, 0.f)
         + fmaxf(ap[(size_t)(t + 3) * NC] * sc + sh, 0.f);
  }
  mout[idx] = acc / (float)Tv;
}

// K6: classifier head.  One block per batch sample.
__global__ __launch_bounds__(256) void k_fc(
    const float* __restrict__ meanb, const float* __restrict__ w1,
    const float* __restrict__ b1, const float* __restrict__ w2,
    const float* __restrict__ b2, float* __restrict__ out) {
  __shared__ float m[NC];
  __shared__ float h[256];
  int tid = threadIdx.x, b = blockIdx.x;
  for (int i4 = tid; i4 < 528; i4 += 256)
    *(float4*)(m + i4 * 4) = *(const float4*)(meanb + b * NC + i4 * 4);
  __syncthreads();
  float acc = b1[tid];
  for (int k = 0; k < NC; k += 8) {
    #pragma unroll
    for (int u = 0; u < 8; u++) acc += m[k + u] * w1[(k + u) * 256 + tid];
  }
  h[tid] = fmaxf(acc, 0.f);
  __syncthreads();
  if (tid < 10) {
    float a = b2[tid];
    for (int k = 0; k < 256; k++) a += h[k] * w2[k * 10 + tid];
    out[b * 10 + tid] = a;
  }
}

// =====================================================================
extern "C" void kernel_launch(void* const* d_in, const int* in_sizes, int n_in,
                              void* d_out, int out_size, void* d_ws, size_t ws_size,
                              hipStream_t stream) {
  const float* x        = (const float*)d_in[0];
  const int*   ei       = (const int*)d_in[1];
  const float* s1_tc1_w = (const float*)d_in[2];
  const float* s1_tc1_b = (const float*)d_in[3];
  const float* s1_cheb_w= (const float*)d_in[4];
  const float* s1_cheb_b= (const float*)d_in[5];
  const float* s1_tc2_w = (const float*)d_in[6];
  const float* s1_tc2_b = (const float*)d_in[7];
  const float* s1_bn_g  = (const float*)d_in[8];
  const float* s1_bn_b  = (const float*)d_in[9];
  const float* s2_tc1_w = (const float*)d_in[10];
  const float* s2_tc1_b = (const float*)d_in[11];
  const float* s2_cheb_w= (const float*)d_in[12];
  const float* s2_cheb_b= (const float*)d_in[13];
  const float* s2_tc2_w = (const float*)d_in[14];
  const float* s2_tc2_b = (const float*)d_in[15];
  const float* s2_bn_g  = (const float*)d_in[16];
  const float* s2_bn_b  = (const float*)d_in[17];
  const float* fc1_w    = (const float*)d_in[18];
  const float* fc1_b    = (const float*)d_in[19];
  const float* fc2_w    = (const float*)d_in[20];
  const float* fc2_b    = (const float*)d_in[21];
  float* ws  = (float*)d_ws;
  float* out = (float*)d_out;

  int chunk = 8;
  while (chunk > 1 &&
         ((size_t)OFF_A + A_ELEMS + (size_t)chunk * SLAB * 2) * 4 > ws_size)
    chunk >>= 1;
  float* A  = ws + OFF_A;
  float* HS = A + A_ELEMS;
  float* CS = HS + (size_t)chunk * SLAB;

  hipMemsetAsync(ws + OFF_ST1, 0, 200 * sizeof(float), stream);
  k_prep<<<1, 256, 0, stream>>>(ei, s1_cheb_w, s2_cheb_w,
                                s1_tc2_w, s2_tc1_w, s2_tc2_w, ws);

  const unsigned short* wt0 = (const unsigned short*)(ws + OFF_WT0);
  const unsigned short* wt1 = (const unsigned short*)(ws + OFF_WT1);
  const unsigned short* wt2 = (const unsigned short*)(ws + OFF_WT2);
  const unsigned short* uf1 = (const unsigned short*)(ws + OFF_UP1);
  const unsigned short* uf2 = (const unsigned short*)(ws + OFF_UP2);

  int nchunks = 32 / chunk;
  int rowsC = chunk * 510 * NN;
  int nblkC = (rowsC + 63) / 64;
  // ---------------- stage 1 ----------------
  for (int ci = 0; ci < nchunks; ci++) {
    int b0 = ci * chunk;
    int total0 = chunk * 510 * NC;
    k_tconv0<<<(total0 + 255) / 256, 256, 0, stream>>>(x, s1_tc1_w, s1_tc1_b,
                                                       HS, b0, total0);
    k_chebmm<<<nblkC, 256, 0, stream>>>(HS, uf1, s1_cheb_b, CS, ws, rowsC);
    k_tconv<<<chunk * NN * 8, 256, 0, stream>>>(CS, 510, 510, wt0, s1_tc2_b,
                                                A + (size_t)b0 * 508 * NC, 508, 508);
  }
  int nSlab1 = (508 + 15) / 16;
  k_bnstats<<<32 * nSlab1, 256, 0, stream>>>(A, 508, 508, ws + OFF_ST1, nSlab1);
  int total4a = 32 * 508 * 528;
  k_bnapply<<<(total4a + 255) / 256, 256, 0, stream>>>(A, 508, 508, ws + OFF_ST1,
                                                       s1_bn_g, s1_bn_b, total4a);
  // ---------------- stage 2 ----------------
  for (int ci = 0; ci < nchunks; ci++) {
    int b0 = ci * chunk;
    k_tconv<<<chunk * NN * 8, 256, 0, stream>>>(A + (size_t)b0 * 508 * NC, 508, 508,
                                                wt1, s2_tc1_b, HS, 510, 506);
    k_chebmm<<<nblkC, 256, 0, stream>>>(HS, uf2, s2_cheb_b, CS, ws, rowsC);
    k_tconv<<<chunk * NN * 8, 256, 0, stream>>>(CS, 510, 506, wt2, s2_tc2_b,
                                                A + (size_t)b0 * 508 * NC, 508, 504);
  }
  int nSlab2 = (504 + 15) / 16;
  k_bnstats<<<32 * nSlab2, 256, 0, stream>>>(A, 508, 504, ws + OFF_ST2, nSlab2);
  k_bnmean<<<(32 * NC) / 256, 256, 0, stream>>>(A, 508, 504, ws + OFF_ST2,
                                                s2_bn_g, s2_bn_b, ws + OFF_MEAN);
  k_fc<<<32, 256, 0, stream>>>(ws + OFF_MEAN, fc1_w, fc1_b, fc2_w, fc2_b, out);
}

// Round 6
// 1610.211 us; speedup vs baseline: 3.3976x; 1.3107x over previous
//
#include <hip/hip_runtime.h>
#include <math.h>

#define NN 33
#define NC 2112   // 33*64

typedef __attribute__((ext_vector_type(8))) short bfrag;
typedef __attribute__((ext_vector_type(4))) float f32x4;

// ---- ws float offsets ----
#define OFF_LT   0          // 33*68: L^T column-doubled  LTd[m][nn]=L[nn%33][m]
#define OFF_L2T  2244       // 33*68: (2*L@L)^T column-doubled
#define OFF_UP1  4488       // 24576 ushort: cheb1 fused U, split-bf16 B-frag blocks
#define OFF_UP2  16776      // cheb2
#define OFF_WT0  29064      // 73728 ushort: s1_tc2 split-bf16 MFMA layout
#define OFF_WT1  65928      // s2_tc1
#define OFF_WT2  102792     // s2_tc2
#define OFF_ST1  139656     // 66 floats
#define OFF_ST2  139722     // 66 floats
#define OFF_MEAN 139856     // 32*2112
#define OFF_A    207440     // big buffer: 32 * 508 * 2112 floats
#define A_ELEMS  34332672ull
#define SLAB     1077120ull // 510*2112 floats per b of scratch

__device__ inline unsigned short f2bf(float x) {
  unsigned int u = __float_as_uint(x);
  unsigned int r = (u + 0x7fffu + ((u >> 16) & 1u)) >> 16;
  return (unsigned short)r;
}
__device__ inline float bf2f(unsigned short h) {
  return __uint_as_float(((unsigned int)h) << 16);
}

// =====================================================================
// K0a: Laplacian only (1 block).  LTd/L2Td column-doubled transposed.
__global__ __launch_bounds__(256) void k_prep_lap(
    const int* __restrict__ ei, float* __restrict__ ws) {
  __shared__ float Lsm[1089];
  __shared__ float L2sm[1089];
  int tid = threadIdx.x;
  for (int i = tid; i < 1089; i += 256) Lsm[i] = 0.f;
  __syncthreads();
  if (tid == 0) {
    float deg[NN];
    for (int n = 0; n < NN; n++) deg[n] = 0.f;
    for (int e = 0; e < 64; e++) deg[ei[e]] += 1.f;
    float dinv[NN];
    for (int n = 0; n < NN; n++) dinv[n] = deg[n] > 0.f ? rsqrtf(deg[n]) : 0.f;
    for (int e = 0; e < 64; e++) {
      int s = ei[e], t = ei[64 + e];
      Lsm[t * NN + s] -= dinv[s] * dinv[t];
    }
  }
  __syncthreads();
  for (int i = tid; i < 1089; i += 256) {
    int r = i / NN, c = i % NN;
    float s = 0.f;
    for (int m = 0; m < NN; m++) s += Lsm[r * NN + m] * Lsm[m * NN + c];
    L2sm[i] = 2.f * s;
  }
  __syncthreads();
  for (int i = tid; i < 33 * 66; i += 256) {
    int m = i / 66, nn = i % 66;
    int n33 = nn < 33 ? nn : nn - 33;
    ws[OFF_LT + m * 68 + nn]  = Lsm[n33 * NN + m];
    ws[OFF_L2T + m * 68 + nn] = L2sm[n33 * NN + m];
  }
}

// K0b: parallel weight prep (grid 288 x 256 = 73728 threads).
__global__ __launch_bounds__(256) void k_prep_w(
    const float* __restrict__ cw1, const float* __restrict__ cw2,
    const float* __restrict__ tw0, const float* __restrict__ tw1,
    const float* __restrict__ tw2, float* __restrict__ ws) {
  int u = blockIdx.x * 256 + threadIdx.x;
  // cheb fused U: addr = (ks*4+nt)*1024 + sp*512 + lane*8 + j
  if (u < 24576) {
    unsigned short* u1 = (unsigned short*)(ws + OFF_UP1);
    unsigned short* u2 = (unsigned short*)(ws + OFF_UP2);
    int j = u & 7;
    int nn = (u >> 3) & 15;
    int q = (u >> 7) & 3;
    int sp = (u >> 9) & 1;
    int blk = u >> 10;
    int nt = blk & 3;
    int ks = blk >> 2;
    int k = ks * 32 + q * 8 + j;
    int d = nt * 16 + nn;
    int s = k >> 6, cc = k & 63;
    float v1 = cw1[(s * 64 + cc) * 64 + d];
    float v2 = cw2[(s * 64 + cc) * 64 + d];
    if (s == 0) { v1 -= cw1[(128 + cc) * 64 + d]; v2 -= cw2[(128 + cc) * 64 + d]; }
    unsigned short h1 = f2bf(v1);
    u1[u] = sp ? f2bf(v1 - bf2f(h1)) : h1;
    unsigned short h2 = f2bf(v2);
    u2[u] = sp ? f2bf(v2 - bf2f(h2)) : h2;
  }
  // tconv split-bf16 (layout verified R4)
  {
    unsigned short* p0 = (unsigned short*)(ws + OFF_WT0);
    unsigned short* p1 = (unsigned short*)(ws + OFF_WT1);
    unsigned short* p2 = (unsigned short*)(ws + OFF_WT2);
    int j  = u & 7;
    int nn_ = (u >> 3) & 15;
    int q  = (u >> 7) & 3;
    int B  = u >> 9;
    int sp = B & 1;
    int B2 = B >> 1;
    int nt = B2 % 12;
    int dk = B2 / 12;
    int ks = dk & 1;
    int dt = dk >> 1;
    int o  = nt * 16 + nn_;
    int ci = ks * 32 + q * 8 + j;
    int src = (o * 64 + ci) * 3 + dt;
    float w0 = tw0[src], w1 = tw1[src], w2 = tw2[src];
    unsigned short h;
    h = f2bf(w0); p0[u] = sp ? f2bf(w0 - bf2f(h)) : h;
    h = f2bf(w1); p1[u] = sp ? f2bf(w1 - bf2f(h)) : h;
    h = f2bf(w2); p2[u] = sp ? f2bf(w2 - bf2f(h)) : h;
  }
}

// =====================================================================
// K1: small gated tconv (Ci=3), x -> HS  (chunk slabs, stride 510 rows)
__global__ __launch_bounds__(256) void k_tconv0(
    const float* __restrict__ x, const float* __restrict__ w,
    const float* __restrict__ bias, float* __restrict__ out,
    int b0, int total) {
  __shared__ float wsm[1728];
  __shared__ float bsm[192];
  int tid = threadIdx.x;
  for (int i = tid; i < 1728; i += 256) wsm[i] = w[i];
  if (tid < 192) bsm[tid] = bias[tid];
  __syncthreads();
  int idx = blockIdx.x * 256 + tid;
  if (idx >= total) return;
  int ch = idx & 63;
  int r = idx >> 6;
  int n = r % NN; r /= NN;
  int t = r % 510;
  int bc = r / 510;
  int b = b0 + bc;
  float aP = bsm[ch], aQ = bsm[64 + ch], aR = bsm[128 + ch];
  const float* xp = x + ((size_t)(b * 512 + t) * NN + n) * 3;
  #pragma unroll
  for (int dt = 0; dt < 3; dt++) {
    float x0 = xp[dt * 99 + 0], x1 = xp[dt * 99 + 1], x2 = xp[dt * 99 + 2];
    aP += x0 * wsm[(ch * 3 + 0) * 3 + dt] + x1 * wsm[(ch * 3 + 1) * 3 + dt] + x2 * wsm[(ch * 3 + 2) * 3 + dt];
    aQ += x0 * wsm[((64 + ch) * 3 + 0) * 3 + dt] + x1 * wsm[((64 + ch) * 3 + 1) * 3 + dt] + x2 * wsm[((64 + ch) * 3 + 2) * 3 + dt];
    aR += x0 * wsm[((128 + ch) * 3 + 0) * 3 + dt] + x1 * wsm[((128 + ch) * 3 + 1) * 3 + dt] + x2 * wsm[((128 + ch) * 3 + 2) * 3 + dt];
  }
  float sg = 1.f / (1.f + __expf(-aQ));
  out[(size_t)(bc * 510 + t) * NC + n * 64 + ch] = fmaxf(aP * sg + aR, 0.f);
}

// =====================================================================
// K2 v4: fused ChebConv, barrier-free.  h read straight from global (L2-hot),
// each wave packs and consumes only its own 16 A-rows.  LDS 50 KB.
__global__ __launch_bounds__(256) void k_chebmm(
    const float* __restrict__ in, const unsigned short* __restrict__ Uf,
    const float* __restrict__ cbias, float* __restrict__ out,
    const float* __restrict__ ws, int totalRows) {
  __shared__ __attribute__((aligned(16))) unsigned short Ah[64 * 196];
  __shared__ __attribute__((aligned(16))) unsigned short Al[64 * 196];

  int tid = threadIdx.x;
  int R0 = blockIdx.x * 64;
  int c = tid & 63;
  int g = __builtin_amdgcn_readfirstlane(tid >> 6);
  int Rg = R0 + g * 16;
  int btg = Rg / 33;
  int n0 = Rg - btg * 33;          // wave-uniform
  int wrap = 33 - n0;              // rr >= wrap -> next bt

  const float* lt  = ws + OFF_LT;
  const float* l2t = ws + OFF_L2T;
  const float* ipA = in + (size_t)btg * NC + c;
  const float* ipB = ipA + NC;
  float z1[16], z2[16];
  #pragma unroll
  for (int rr = 0; rr < 16; rr++) { z1[rr] = 0.f; z2[rr] = 0.f; }
  for (int m = 0; m < NN; m++) {
    float hvA = ipA[m * 64];
    float hvB = ipB[m * 64];
    const float* ltm  = lt + m * 68 + n0;
    const float* l2tm = l2t + m * 68 + n0;
    #pragma unroll
    for (int rr = 0; rr < 16; rr++) {
      float hv = (rr < wrap) ? hvA : hvB;
      z1[rr] += ltm[rr] * hv;
      z2[rr] += l2tm[rr] * hv;
    }
  }
  // pack h / Z1 / Z2 split-bf16 (wave-local rows; no barrier needed)
  #pragma unroll
  for (int rr = 0; rr < 16; rr++) {
    int n = n0 + rr, bto = 0;
    if (n >= 33) { n -= 33; bto = 1; }
    int r = g * 16 + rr;
    float hcv = in[(size_t)(btg + bto) * NC + n * 64 + c];
    unsigned short hh = f2bf(hcv);
    Ah[r * 196 + c] = hh;
    Al[r * 196 + c] = f2bf(hcv - bf2f(hh));
    unsigned short zh1 = f2bf(z1[rr]);
    Ah[r * 196 + 64 + c] = zh1;
    Al[r * 196 + 64 + c] = f2bf(z1[rr] - bf2f(zh1));
    unsigned short zh2 = f2bf(z2[rr]);
    Ah[r * 196 + 128 + c] = zh2;
    Al[r * 196 + 128 + c] = f2bf(z2[rr] - bf2f(zh2));
  }

  // ---- MFMA: out[r][d] = sum_k A[r][k] U[k][d], K=192, N=64 ----
  int lane = tid & 63;
  int m15 = lane & 15, q = lane >> 4;
  f32x4 acc[4];
  #pragma unroll
  for (int nt = 0; nt < 4; nt++) acc[nt] = (f32x4){0.f, 0.f, 0.f, 0.f};
  #pragma unroll
  for (int ks = 0; ks < 6; ks++) {
    int aoff = (g * 16 + m15) * 196 + ks * 32 + q * 8;
    bfrag ah = *(const bfrag*)(Ah + aoff);
    bfrag al = *(const bfrag*)(Al + aoff);
    #pragma unroll
    for (int nt = 0; nt < 4; nt++) {
      const unsigned short* bp = Uf + (ks * 4 + nt) * 1024 + lane * 8;
      bfrag bh = *(const bfrag*)bp;
      bfrag bl = *(const bfrag*)(bp + 512);
      acc[nt] = __builtin_amdgcn_mfma_f32_16x16x32_bf16(ah, bh, acc[nt], 0, 0, 0);
      acc[nt] = __builtin_amdgcn_mfma_f32_16x16x32_bf16(ah, bl, acc[nt], 0, 0, 0);
      acc[nt] = __builtin_amdgcn_mfma_f32_16x16x32_bf16(al, bh, acc[nt], 0, 0, 0);
    }
  }
  #pragma unroll
  for (int nt = 0; nt < 4; nt++) {
    int d = nt * 16 + m15;
    float bd = cbias[d];
    #pragma unroll
    for (int rr = 0; rr < 4; rr++) {
      int R = R0 + g * 16 + q * 4 + rr;
      if (R < totalRows)
        out[(size_t)R * 64 + d] = fmaxf(acc[nt][rr] + bd, 0.f);
    }
  }
}

// =====================================================================
// K3 v6: gated tconv via split-bf16 MFMA; B in registers from global
// (L2-hot), A-only LDS (19 KB), in-register gating, fused BN-in / stats-out.
// Wave = (waveM, aPair): nt = 2*ap + e + 4*gate  ->  lane owns P,Q,R of
// channel ch = (2*ap+e)*16 + m15 for rows waveM*32+mi*16+q*4+rr.
__global__ __launch_bounds__(256) void k_tconv(
    const float* __restrict__ in, int inStride, int Tin,
    const unsigned short* __restrict__ wsp, const float* __restrict__ bias,
    float* __restrict__ out, int outStride, int Tout,
    const float* __restrict__ bnSt, const float* __restrict__ bnG,
    const float* __restrict__ bnB, float bnCnt, float* __restrict__ statsOut) {
  __shared__ __attribute__((aligned(16))) unsigned short Ah[66 * 72];
  __shared__ __attribute__((aligned(16))) unsigned short Al[66 * 72];
  __shared__ float red[8];
  int tid = threadIdx.x;
  int ntt = (Tout + 63) >> 6;
  int tpb = NN * ntt;
  int bc = blockIdx.x / tpb, r = blockIdx.x % tpb;
  int n = r / ntt, tt = r % ntt;
  int t0 = tt << 6;
  const float* ip = in + (size_t)bc * inStride * NC + n * 64;

  float sc = 1.f, sh = 0.f;
  if (bnSt) {
    float mean = bnSt[n] / bnCnt;
    float var = bnSt[33 + n] / bnCnt - mean * mean;
    sc = rsqrtf(var + 1e-5f) * bnG[n];
    sh = bnB[n] - mean * sc;
  }
  for (int i = tid; i < 66 * 16; i += 256) {
    int row = i >> 4, c4 = i & 15;
    float4 v = make_float4(0.f, 0.f, 0.f, 0.f);
    if (t0 + row < Tin) v = *(const float4*)(ip + (size_t)(t0 + row) * NC + c4 * 4);
    if (bnSt) {
      v.x = fmaxf(v.x * sc + sh, 0.f);
      v.y = fmaxf(v.y * sc + sh, 0.f);
      v.z = fmaxf(v.z * sc + sh, 0.f);
      v.w = fmaxf(v.w * sc + sh, 0.f);
    }
    unsigned short h0 = f2bf(v.x), h1 = f2bf(v.y), h2 = f2bf(v.z), h3 = f2bf(v.w);
    unsigned short l0 = f2bf(v.x - bf2f(h0)), l1 = f2bf(v.y - bf2f(h1));
    unsigned short l2 = f2bf(v.z - bf2f(h2)), l3 = f2bf(v.w - bf2f(h3));
    uint2 ph, pl;
    ph.x = (unsigned)h0 | ((unsigned)h1 << 16); ph.y = (unsigned)h2 | ((unsigned)h3 << 16);
    pl.x = (unsigned)l0 | ((unsigned)l1 << 16); pl.y = (unsigned)l2 | ((unsigned)l3 << 16);
    *(uint2*)(Ah + row * 72 + c4 * 4) = ph;
    *(uint2*)(Al + row * 72 + c4 * 4) = pl;
  }
  __syncthreads();

  int lane = tid & 63;
  int wv = tid >> 6;
  int waveM = wv >> 1, ap = wv & 1;
  int m15 = lane & 15, q = lane >> 4;

  f32x4 acc[2][6];   // acc[mi][j*2+e], gate j, chan-group e
  #pragma unroll
  for (int mi = 0; mi < 2; mi++)
    #pragma unroll
    for (int ni = 0; ni < 6; ni++) acc[mi][ni] = (f32x4){0.f, 0.f, 0.f, 0.f};

  for (int dt = 0; dt < 3; dt++) {
    const unsigned short* wdt = wsp + (size_t)dt * 24576;
    #pragma unroll
    for (int ks = 0; ks < 2; ks++) {
      bfrag ah[2], al[2];
      #pragma unroll
      for (int mi = 0; mi < 2; mi++) {
        int row = waveM * 32 + mi * 16 + m15 + dt;
        int off = row * 72 + ks * 32 + q * 8;
        ah[mi] = *(const bfrag*)(Ah + off);
        al[mi] = *(const bfrag*)(Al + off);
      }
      #pragma unroll
      for (int j = 0; j < 3; j++)
        #pragma unroll
        for (int e = 0; e < 2; e++) {
          int nt = 2 * ap + e + 4 * j;
          const unsigned short* bp = wdt + ((ks * 12 + nt) * 2) * 512 + lane * 8;
          bfrag bh = *(const bfrag*)bp;
          bfrag bl = *(const bfrag*)(bp + 512);
          #pragma unroll
          for (int mi = 0; mi < 2; mi++) {
            acc[mi][j * 2 + e] = __builtin_amdgcn_mfma_f32_16x16x32_bf16(ah[mi], bh, acc[mi][j * 2 + e], 0, 0, 0);
            acc[mi][j * 2 + e] = __builtin_amdgcn_mfma_f32_16x16x32_bf16(ah[mi], bl, acc[mi][j * 2 + e], 0, 0, 0);
            acc[mi][j * 2 + e] = __builtin_amdgcn_mfma_f32_16x16x32_bf16(al[mi], bh, acc[mi][j * 2 + e], 0, 0, 0);
          }
        }
    }
  }

  // ---- in-register gating + store + stats ----
  float ssum = 0.f, sq = 0.f;
  #pragma unroll
  for (int mi = 0; mi < 2; mi++)
    #pragma unroll
    for (int e = 0; e < 2; e++) {
      int ch = (2 * ap + e) * 16 + m15;
      float bP = bias[ch], bQ = bias[64 + ch], bR = bias[128 + ch];
      #pragma unroll
      for (int rr = 0; rr < 4; rr++) {
        int t = t0 + waveM * 32 + mi * 16 + q * 4 + rr;
        float P = acc[mi][e][rr] + bP;
        float Q = acc[mi][2 + e][rr] + bQ;
        float Rv = acc[mi][4 + e][rr] + bR;
        float sg = 1.f / (1.f + __expf(-Q));
        float h = fmaxf(P * sg + Rv, 0.f);
        if (t < Tout) {
          out[(size_t)(bc * outStride + t) * NC + n * 64 + ch] = h;
          ssum += h; sq += h * h;
        }
      }
    }
  if (statsOut) {
    #pragma unroll
    for (int d = 32; d > 0; d >>= 1) {
      ssum += __shfl_down(ssum, d);
      sq += __shfl_down(sq, d);
    }
    if (lane == 0) { red[wv] = ssum; red[4 + wv] = sq; }
    __syncthreads();
    if (tid == 0) {
      atomicAdd(&statsOut[n], red[0] + red[1] + red[2] + red[3]);
      atomicAdd(&statsOut[33 + n], red[4] + red[5] + red[6] + red[7]);
    }
  }
}

// =====================================================================
// K5b: BN apply + relu + mean over T (stage 2), no materialization.
__global__ __launch_bounds__(256) void k_bnmean(
    const float* __restrict__ A, int stride, int Tv,
    const float* __restrict__ st, const float* __restrict__ gg,
    const float* __restrict__ bb, float* __restrict__ mout) {
  int idx = blockIdx.x * 256 + threadIdx.x;   // 32*2112
  int p = idx % NC, b = idx / NC;
  int n = p >> 6;
  float cnt = (float)(32 * Tv * 64);
  float mean = st[n] / cnt;
  float var = st[33 + n] / cnt - mean * mean;
  float sc = rsqrtf(var + 1e-5f) * gg[n];
  float sh = bb[n] - mean * sc;
  float acc = 0.f;
  const float* ap = A + (size_t)b * stride * NC + p;
  for (int t = 0; t < Tv; t += 4) {
    acc += fmaxf(ap[(size_t)t * NC] * sc + sh, 0.f)
         + fmaxf(ap[(size_t)(t + 1) * NC] * sc + sh, 0.f)
         + fmaxf(ap[(size_t)(t + 2) * NC] * sc + sh, 0.f)
         + fmaxf(ap[(size_t)(t + 3) * NC] * sc + sh, 0.f);
  }
  mout[idx] = acc / (float)Tv;
}

// K6: classifier head.  One block per batch sample.
__global__ __launch_bounds__(256) void k_fc(
    const float* __restrict__ meanb, const float* __restrict__ w1,
    const float* __restrict__ b1, const float* __restrict__ w2,
    const float* __restrict__ b2, float* __restrict__ out) {
  __shared__ float m[NC];
  __shared__ float h[256];
  int tid = threadIdx.x, b = blockIdx.x;
  for (int i4 = tid; i4 < 528; i4 += 256)
    *(float4*)(m + i4 * 4) = *(const float4*)(meanb + b * NC + i4 * 4);
  __syncthreads();
  float acc = b1[tid];
  for (int k = 0; k < NC; k += 8) {
    #pragma unroll
    for (int u = 0; u < 8; u++) acc += m[k + u] * w1[(k + u) * 256 + tid];
  }
  h[tid] = fmaxf(acc, 0.f);
  __syncthreads();
  if (tid < 10) {
    float a = b2[tid];
    for (int k = 0; k < 256; k++) a += h[k] * w2[k * 10 + tid];
    out[b * 10 + tid] = a;
  }
}

// =====================================================================
extern "C" void kernel_launch(void* const* d_in, const int* in_sizes, int n_in,
                              void* d_out, int out_size, void* d_ws, size_t ws_size,
                              hipStream_t stream) {
  const float* x        = (const float*)d_in[0];
  const int*   ei       = (const int*)d_in[1];
  const float* s1_tc1_w = (const float*)d_in[2];
  const float* s1_tc1_b = (const float*)d_in[3];
  const float* s1_cheb_w= (const float*)d_in[4];
  const float* s1_cheb_b= (const float*)d_in[5];
  const float* s1_tc2_w = (const float*)d_in[6];
  const float* s1_tc2_b = (const float*)d_in[7];
  const float* s1_bn_g  = (const float*)d_in[8];
  const float* s1_bn_b  = (const float*)d_in[9];
  const float* s2_tc1_w = (const float*)d_in[10];
  const float* s2_tc1_b = (const float*)d_in[11];
  const float* s2_cheb_w= (const float*)d_in[12];
  const float* s2_cheb_b= (const float*)d_in[13];
  const float* s2_tc2_w = (const float*)d_in[14];
  const float* s2_tc2_b = (const float*)d_in[15];
  const float* s2_bn_g  = (const float*)d_in[16];
  const float* s2_bn_b  = (const float*)d_in[17];
  const float* fc1_w    = (const float*)d_in[18];
  const float* fc1_b    = (const float*)d_in[19];
  const float* fc2_w    = (const float*)d_in[20];
  const float* fc2_b    = (const float*)d_in[21];
  float* ws  = (float*)d_ws;
  float* out = (float*)d_out;

  int chunk = 8;
  while (chunk > 1 &&
         ((size_t)OFF_A + A_ELEMS + (size_t)chunk * SLAB * 2) * 4 > ws_size)
    chunk >>= 1;
  float* A  = ws + OFF_A;
  float* HS = A + A_ELEMS;
  float* CS = HS + (size_t)chunk * SLAB;

  hipMemsetAsync(ws + OFF_ST1, 0, 200 * sizeof(float), stream);
  k_prep_lap<<<1, 256, 0, stream>>>(ei, ws);
  k_prep_w<<<288, 256, 0, stream>>>(s1_cheb_w, s2_cheb_w,
                                    s1_tc2_w, s2_tc1_w, s2_tc2_w, ws);

  const unsigned short* wt0 = (const unsigned short*)(ws + OFF_WT0);
  const unsigned short* wt1 = (const unsigned short*)(ws + OFF_WT1);
  const unsigned short* wt2 = (const unsigned short*)(ws + OFF_WT2);
  const unsigned short* uf1 = (const unsigned short*)(ws + OFF_UP1);
  const unsigned short* uf2 = (const unsigned short*)(ws + OFF_UP2);

  int nchunks = 32 / chunk;
  int rowsC = chunk * 510 * NN;
  int nblkC = (rowsC + 63) / 64;
  float cnt1 = (float)(32 * 508 * 64);
  // ---------------- stage 1 ----------------
  for (int ci = 0; ci < nchunks; ci++) {
    int b0 = ci * chunk;
    int total0 = chunk * 510 * NC;
    k_tconv0<<<(total0 + 255) / 256, 256, 0, stream>>>(x, s1_tc1_w, s1_tc1_b,
                                                       HS, b0, total0);
    k_chebmm<<<nblkC, 256, 0, stream>>>(HS, uf1, s1_cheb_b, CS, ws, rowsC);
    k_tconv<<<chunk * NN * 8, 256, 0, stream>>>(CS, 510, 510, wt0, s1_tc2_b,
                                                A + (size_t)b0 * 508 * NC, 508, 508,
                                                nullptr, nullptr, nullptr, 1.f,
                                                ws + OFF_ST1);
  }
  // ---------------- stage 2 ----------------
  for (int ci = 0; ci < nchunks; ci++) {
    int b0 = ci * chunk;
    k_tconv<<<chunk * NN * 8, 256, 0, stream>>>(A + (size_t)b0 * 508 * NC, 508, 508,
                                                wt1, s2_tc1_b, HS, 510, 506,
                                                ws + OFF_ST1, s1_bn_g, s1_bn_b, cnt1,
                                                nullptr);
    k_chebmm<<<nblkC, 256, 0, stream>>>(HS, uf2, s2_cheb_b, CS, ws, rowsC);
    k_tconv<<<chunk * NN * 8, 256, 0, stream>>>(CS, 510, 506, wt2, s2_tc2_b,
                                                A + (size_t)b0 * 508 * NC, 508, 504,
                                                nullptr, nullptr, nullptr, 1.f,
                                                ws + OFF_ST2);
  }
  k_bnmean<<<(32 * NC) / 256, 256, 0, stream>>>(A, 508, 504, ws + OFF_ST2,
                                                s2_bn_g, s2_bn_b, ws + OFF_MEAN);
  k_fc<<<32, 256, 0, stream>>>(ws + OFF_MEAN, fc1_w, fc1_b, fc2_w, fc2_b, out);
}